// Round 25
// baseline (375.822 us; speedup 1.0000x reference)
//
#include <hip/hip_runtime.h>
#include <hip/hip_bf16.h>
#include <math.h>

#define HW 16384

typedef __attribute__((ext_vector_type(8))) short bf16x8;
typedef __attribute__((ext_vector_type(4))) float f32x4;

__device__ __forceinline__ unsigned short f2bf(float a)
{
    __hip_bfloat16 h = __float2bfloat16(a);   // RNE, native v_cvt
    return __builtin_bit_cast(unsigned short, h);
}
__device__ __forceinline__ unsigned f2bf_pk(float a, float b)
{
    return (unsigned)f2bf(a) | ((unsigned)f2bf(b) << 16);
}
__device__ __forceinline__ float bf2f(unsigned short u)
{
    return __uint_as_float(((unsigned)u) << 16);
}
__device__ __forceinline__ float sigmoidf_(float v) { return 1.f / (1.f + expf(-v)); }

__device__ __forceinline__ float2 cmul(float2 a, float2 b)
{
    return make_float2(a.x * b.x - a.y * b.y, a.x * b.y + a.y * b.x);
}

// ---------------------------------------------------------------------------
// wprep: 7 weight matrices -> bf16 in pre-swizzled LDS chunk order.
// ---------------------------------------------------------------------------
__global__ __launch_bounds__(256)
void wprep_k(const float* __restrict__ w0, const float* __restrict__ w1,
             const float* __restrict__ w2, const float* __restrict__ w3,
             const float* __restrict__ w4, const float* __restrict__ w5,
             const float* __restrict__ w6, int4* __restrict__ Wbf4)
{
    int m = blockIdx.x >> 3;
    int slot = (blockIdx.x & 7) * 256 + threadIdx.x;   // 0..2047
    const float* src;
    switch (m) {
        case 0: src = w0; break;
        case 1: src = w1; break;
        case 2: src = w2; break;
        case 3: src = w3; break;
        case 4: src = w4; break;
        case 5: src = w5; break;
        default: src = w6; break;
    }
    int o = slot >> 4;
    int c16 = (slot & 15) ^ (o & 7);
    const float* p = src + o * 128 + c16 * 8;
    int4 pk;
    pk.x = f2bf_pk(p[0], p[1]); pk.y = f2bf_pk(p[2], p[3]);
    pk.z = f2bf_pk(p[4], p[5]); pk.w = f2bf_pk(p[6], p[7]);
    Wbf4[m * 2048 + slot] = pk;
}

// ---------------------------------------------------------------------------
// head: stage x once; V = Wv @ x ; swb = W_ff2 @ gelu(W_ff1 @ x);
// also emits xb = bf16(x) for gram/fft reuse.
// ---------------------------------------------------------------------------
__global__ __launch_bounds__(256)
void head_k(const float* __restrict__ x, const int4* __restrict__ wv,
            const int4* __restrict__ w1, const int4* __restrict__ w2,
            unsigned short* __restrict__ V, unsigned short* __restrict__ swb,
            unsigned short* __restrict__ xb)
{
    __shared__ short WL[128 * 128];   // 32 KB
    __shared__ short XLx[64 * 128];   // 16 KB
    __shared__ short XM[64 * 128];    // 16 KB
    int t = threadIdx.x;
    int gb = blockIdx.x;
    int b = gb >> 8;
    int n0 = (gb & 255) << 6;

    #pragma unroll
    for (int it = 0; it < 8; ++it)
        ((int4*)WL)[it * 256 + t] = wv[it * 256 + t];

    const float* inb = x + (size_t)b * 128 * HW + n0;
    int nl = t & 63;
    #pragma unroll
    for (int it = 0; it < 4; ++it) {
        int c8 = (t >> 6) + it * 4;
        float v[8];
        unsigned short vb[8];
        #pragma unroll
        for (int j = 0; j < 8; ++j) {
            v[j] = inb[(size_t)(c8 * 8 + j) * HW + nl];
            vb[j] = f2bf(v[j]);
            xb[((size_t)(b * 128) + c8 * 8 + j) * HW + n0 + nl] = vb[j];
        }
        int4 p;
        p.x = (int)((unsigned)vb[0] | ((unsigned)vb[1] << 16));
        p.y = (int)((unsigned)vb[2] | ((unsigned)vb[3] << 16));
        p.z = (int)((unsigned)vb[4] | ((unsigned)vb[5] << 16));
        p.w = (int)((unsigned)vb[6] | ((unsigned)vb[7] << 16));
        ((int4*)XLx)[nl * 16 + (c8 ^ (nl & 7))] = p;
    }
    __syncthreads();

    int l = t & 63, w = t >> 6, kg = l >> 4, l15 = l & 15, l7 = l15 & 7;

    // ---- GEMM1: V = Wv @ x ----
    f32x4 acc[2][4];
    #pragma unroll
    for (int mf = 0; mf < 2; ++mf)
        #pragma unroll
        for (int nf = 0; nf < 4; ++nf) acc[mf][nf] = (f32x4){0.f, 0.f, 0.f, 0.f};
    #pragma unroll
    for (int ks = 0; ks < 4; ++ks) {
        int ch = ks * 4 + kg;
        bf16x8 A0 = ((const bf16x8*)WL)[(w * 32 + l15) * 16 + (ch ^ l7)];
        bf16x8 A1 = ((const bf16x8*)WL)[(w * 32 + 16 + l15) * 16 + (ch ^ l7)];
        #pragma unroll
        for (int nf = 0; nf < 4; ++nf) {
            bf16x8 Bf = ((const bf16x8*)XLx)[(nf * 16 + l15) * 16 + (ch ^ l7)];
            acc[0][nf] = __builtin_amdgcn_mfma_f32_16x16x32_bf16(A0, Bf, acc[0][nf], 0, 0, 0);
            acc[1][nf] = __builtin_amdgcn_mfma_f32_16x16x32_bf16(A1, Bf, acc[1][nf], 0, 0, 0);
        }
    }
    #pragma unroll
    for (int mf = 0; mf < 2; ++mf)
        #pragma unroll
        for (int nf = 0; nf < 4; ++nf)
            #pragma unroll
            for (int i = 0; i < 4; ++i) {
                int row = w * 32 + mf * 16 + kg * 4 + i;
                int col = n0 + nf * 16 + l15;
                V[((size_t)b * 128 + row) * HW + col] = f2bf(acc[mf][nf][i]);
            }
    __syncthreads();

    #pragma unroll
    for (int it = 0; it < 8; ++it)
        ((int4*)WL)[it * 256 + t] = w1[it * 256 + t];
    __syncthreads();

    // ---- GEMM2: mid = ff1 @ x ----
    #pragma unroll
    for (int mf = 0; mf < 2; ++mf)
        #pragma unroll
        for (int nf = 0; nf < 4; ++nf) acc[mf][nf] = (f32x4){0.f, 0.f, 0.f, 0.f};
    #pragma unroll
    for (int ks = 0; ks < 4; ++ks) {
        int ch = ks * 4 + kg;
        bf16x8 A0 = ((const bf16x8*)WL)[(w * 32 + l15) * 16 + (ch ^ l7)];
        bf16x8 A1 = ((const bf16x8*)WL)[(w * 32 + 16 + l15) * 16 + (ch ^ l7)];
        #pragma unroll
        for (int nf = 0; nf < 4; ++nf) {
            bf16x8 Bf = ((const bf16x8*)XLx)[(nf * 16 + l15) * 16 + (ch ^ l7)];
            acc[0][nf] = __builtin_amdgcn_mfma_f32_16x16x32_bf16(A0, Bf, acc[0][nf], 0, 0, 0);
            acc[1][nf] = __builtin_amdgcn_mfma_f32_16x16x32_bf16(A1, Bf, acc[1][nf], 0, 0, 0);
        }
    }
    __syncthreads();

    #pragma unroll
    for (int it = 0; it < 8; ++it)
        ((int4*)WL)[it * 256 + t] = w2[it * 256 + t];
    #pragma unroll
    for (int mf = 0; mf < 2; ++mf)
        #pragma unroll
        for (int nf = 0; nf < 4; ++nf) {
            float g4[4];
            #pragma unroll
            for (int i = 0; i < 4; ++i) {
                float v = acc[mf][nf][i];
                g4[i] = 0.5f * v * (1.0f + erff(v * 0.70710678118654752f));
            }
            int col = nf * 16 + l15;
            int r0 = w * 32 + mf * 16 + kg * 4;
            int octet = r0 >> 3;
            uint2 pk2;
            pk2.x = f2bf_pk(g4[0], g4[1]);
            pk2.y = f2bf_pk(g4[2], g4[3]);
            ((uint2*)XM)[(col * 16 + (octet ^ (col & 7))) * 2 + (kg & 1)] = pk2;
        }
    __syncthreads();

    // ---- GEMM3: swb = ff2 @ mid ----
    f32x4 acc2[2][4];
    #pragma unroll
    for (int mf = 0; mf < 2; ++mf)
        #pragma unroll
        for (int nf = 0; nf < 4; ++nf) acc2[mf][nf] = (f32x4){0.f, 0.f, 0.f, 0.f};
    #pragma unroll
    for (int ks = 0; ks < 4; ++ks) {
        int ch = ks * 4 + kg;
        bf16x8 A0 = ((const bf16x8*)WL)[(w * 32 + l15) * 16 + (ch ^ l7)];
        bf16x8 A1 = ((const bf16x8*)WL)[(w * 32 + 16 + l15) * 16 + (ch ^ l7)];
        #pragma unroll
        for (int nf = 0; nf < 4; ++nf) {
            bf16x8 Bf = ((const bf16x8*)XM)[(nf * 16 + l15) * 16 + (ch ^ l7)];
            acc2[0][nf] = __builtin_amdgcn_mfma_f32_16x16x32_bf16(A0, Bf, acc2[0][nf], 0, 0, 0);
            acc2[1][nf] = __builtin_amdgcn_mfma_f32_16x16x32_bf16(A1, Bf, acc2[1][nf], 0, 0, 0);
        }
    }
    #pragma unroll
    for (int mf = 0; mf < 2; ++mf)
        #pragma unroll
        for (int nf = 0; nf < 4; ++nf)
            #pragma unroll
            for (int i = 0; i < 4; ++i) {
                int row = w * 32 + mf * 16 + kg * 4 + i;
                int col = n0 + nf * 16 + l15;
                swb[((size_t)b * 128 + row) * HW + col] = f2bf(acc2[mf][nf][i]);
            }
}

// ---------------------------------------------------------------------------
// depthwise 3x3 SAME, LDS-tiled: one block per (b,c) image plane (32 KB).
// ---------------------------------------------------------------------------
__global__ __launch_bounds__(256)
void dwconv_k(const unsigned short* __restrict__ V, const float* __restrict__ Wdw,
              unsigned short* __restrict__ vcb)
{
    __shared__ unsigned short Vt[128 * 128];   // 32 KB
    int t = threadIdx.x;
    int bc = blockIdx.x;
    int c = bc & 127;
    const unsigned short* vin = V + (size_t)bc * HW;
    #pragma unroll
    for (int i = 0; i < 16; ++i) {
        int idx = i * 256 + t;                 // uint2 chunks (4 px)
        ((uint2*)Vt)[idx] = ((const uint2*)vin)[idx];
    }
    float wf[9];
    #pragma unroll
    for (int i = 0; i < 9; ++i) wf[i] = Wdw[c * 9 + i];
    __syncthreads();
    #pragma unroll
    for (int i = 0; i < 16; ++i) {
        int q = i * 256 + t;
        int y = q >> 5;
        int x0 = (q & 31) << 2;
        float a0 = 0.f, a1 = 0.f, a2 = 0.f, a3 = 0.f;
        #pragma unroll
        for (int dy = 0; dy < 3; ++dy) {
            int yy = y + dy - 1;
            if (yy < 0 || yy > 127) continue;
            const unsigned short* r = Vt + yy * 128;
            uint2 mu = *(const uint2*)(r + x0);
            float m0 = bf2f((unsigned short)(mu.x & 0xFFFF));
            float m1 = bf2f((unsigned short)(mu.x >> 16));
            float m2 = bf2f((unsigned short)(mu.y & 0xFFFF));
            float m3 = bf2f((unsigned short)(mu.y >> 16));
            float left  = (x0 > 0)   ? bf2f(r[x0 - 1]) : 0.f;
            float right = (x0 < 124) ? bf2f(r[x0 + 4]) : 0.f;
            float w0 = wf[dy * 3], w1 = wf[dy * 3 + 1], w2 = wf[dy * 3 + 2];
            a0 += w0 * left + w1 * m0 + w2 * m1;
            a1 += w0 * m0   + w1 * m1 + w2 * m2;
            a2 += w0 * m1   + w1 * m2 + w2 * m3;
            a3 += w0 * m2   + w1 * m3 + w2 * right;
        }
        uint2 r2;
        r2.x = f2bf_pk(a0, a1);
        r2.y = f2bf_pk(a2, a3);
        *(uint2*)(vcb + (size_t)bc * HW + y * 128 + x0) = r2;
    }
}

// ---------------------------------------------------------------------------
// MFMA Gram partials (reads pre-converted xb: pure copy staging)
// ---------------------------------------------------------------------------
__global__ __launch_bounds__(256)
void gram_mfma_k(const unsigned short* __restrict__ xb, float* __restrict__ Gp)
{
    __shared__ short XL[128 * 128];
    int t = threadIdx.x;
    int blk = blockIdx.x;
    int b = blk >> 5, ks = blk & 31;
    const unsigned short* xbb = xb + (size_t)b * 128 * HW + ks * 512;
    int l = t & 63, w = t >> 6, kg = l >> 4, l15 = l & 15, l7 = l15 & 7;

    f32x4 acc[2][8];
    #pragma unroll
    for (int mf = 0; mf < 2; ++mf)
        #pragma unroll
        for (int nf = 0; nf < 8; ++nf) acc[mf][nf] = (f32x4){0.f, 0.f, 0.f, 0.f};

    for (int kc = 0; kc < 4; ++kc) {
        __syncthreads();
        #pragma unroll
        for (int it = 0; it < 8; ++it) {
            int g = it * 256 + t;
            int row = g >> 4, oct = g & 15;
            ((int4*)XL)[row * 16 + (oct ^ (row & 7))] =
                *(const int4*)(xbb + (size_t)row * HW + kc * 128 + oct * 8);
        }
        __syncthreads();
        #pragma unroll
        for (int s = 0; s < 4; ++s) {
            int oct = s * 4 + kg;
            bf16x8 A0 = ((const bf16x8*)XL)[(w * 32 + l15) * 16 + (oct ^ l7)];
            bf16x8 A1 = ((const bf16x8*)XL)[(w * 32 + 16 + l15) * 16 + (oct ^ l7)];
            #pragma unroll
            for (int nf = 0; nf < 8; ++nf) {
                bf16x8 Bf = ((const bf16x8*)XL)[(nf * 16 + l15) * 16 + (oct ^ l7)];
                acc[0][nf] = __builtin_amdgcn_mfma_f32_16x16x32_bf16(A0, Bf, acc[0][nf], 0, 0, 0);
                acc[1][nf] = __builtin_amdgcn_mfma_f32_16x16x32_bf16(A1, Bf, acc[1][nf], 0, 0, 0);
            }
        }
    }
    float* gp = Gp + (size_t)blk * 16384;
    #pragma unroll
    for (int mf = 0; mf < 2; ++mf)
        #pragma unroll
        for (int nf = 0; nf < 8; ++nf)
            #pragma unroll
            for (int i = 0; i < 4; ++i) {
                int row = w * 32 + mf * 16 + kg * 4 + i;
                int col = nf * 16 + l15;
                gp[row * 128 + col] = acc[mf][nf][i];
            }
}

__global__ void gram_reduce_k(const float* __restrict__ Gp, float* __restrict__ G)
{
    int idx = blockIdx.x * 256 + threadIdx.x;
    int b = idx >> 14;
    int ij = idx & 16383;
    const float* gp = Gp + (size_t)(b * 32) * 16384 + ij;
    float s = 0.f;
    #pragma unroll
    for (int ks = 0; ks < 32; ++ks) s += gp[(size_t)ks * 16384];
    G[idx] = s;
}

// ---------------------------------------------------------------------------
// S_h = softmax( (Wq_h G Wk_h^T) * scale[h] )
// ---------------------------------------------------------------------------
__global__ __launch_bounds__(256)
void attn_s2_k(const float* __restrict__ G, const float* __restrict__ Wqkv,
               const float* __restrict__ scale, float* __restrict__ S)
{
    __shared__ float Wq[16][129];
    __shared__ float Wk[16][129];
    __shared__ float Ts[16][129];
    int bh = blockIdx.x;
    int b = bh >> 3, h = bh & 7;
    int t = threadIdx.x;
    #pragma unroll
    for (int i = 0; i < 8; ++i) {
        int idx = t + i * 256;
        int r = idx >> 7, ci = idx & 127;
        Wq[r][ci] = Wqkv[(size_t)(h * 16 + r) * 128 + ci];
        Wk[r][ci] = Wqkv[(size_t)(128 + h * 16 + r) * 128 + ci];
    }
    __syncthreads();
    const float* Gb = G + (size_t)b * 16384;
    #pragma unroll
    for (int i = 0; i < 8; ++i) {
        int idx = t + i * 256;
        int c = idx >> 7, col = idx & 127;
        float s = 0.f;
        #pragma unroll 8
        for (int ci = 0; ci < 128; ++ci)
            s += Wq[c][ci] * Gb[ci * 128 + col];
        Ts[c][col] = s;
    }
    __syncthreads();
    int c = t >> 4, d = t & 15;
    float s = 0.f;
    #pragma unroll 8
    for (int col = 0; col < 128; ++col)
        s += Ts[c][col] * Wk[d][col];
    s *= scale[h];
    float m = s;
    #pragma unroll
    for (int w = 1; w < 16; w <<= 1)
        m = fmaxf(m, __shfl_xor(m, w, 64));
    float e = expf(s - m);
    float sum = e;
    #pragma unroll
    for (int w = 1; w < 16; w <<= 1)
        sum += __shfl_xor(sum, w, 64);
    S[(size_t)bh * 256 + t] = e / sum;
}

// ---------------------------------------------------------------------------
// fused tail: PV+proj_s (out_s in LDS only) -> proj_f -> gates -> output.
// LDS 72KB: WL 32 (Wps->Wpf->Wgsf->Wgfs) + XP 16 + XS 16 + SL 8. 2 blocks/CU.
// ---------------------------------------------------------------------------
__global__ __launch_bounds__(256)
void tail_k(const float* __restrict__ x,
            const unsigned short* __restrict__ pre,
            const unsigned short* __restrict__ V,
            const unsigned short* __restrict__ vcb,
            const float* __restrict__ S,
            const int4* __restrict__ wps,
            const int4* __restrict__ wpf,
            const int4* __restrict__ wgsf, const float* __restrict__ bgsf,
            const int4* __restrict__ wgfs, const float* __restrict__ bgfs,
            float* __restrict__ out)
{
    __shared__ short WL[128 * 128];   // 32 KB
    __shared__ short XP[64 * 128];    // 16 KB (PV -> pre^T -> out_f^T)
    __shared__ short XS[64 * 128];    // 16 KB (out_s^T, intact to the end)
    __shared__ float SL[2048];        //  8 KB
    int t = threadIdx.x;
    int gb = blockIdx.x;
    int T = (gb & 7) * 256 + (gb >> 3);   // XCD swizzle (2048 % 8 == 0)
    int b = T >> 8;
    int n0 = (T & 255) << 6;

    // ---- stage WL=Wps + SL=S ----
    #pragma unroll
    for (int it = 0; it < 8; ++it)
        ((int4*)WL)[it * 256 + t] = wps[it * 256 + t];
    #pragma unroll
    for (int i = 0; i < 8; ++i)
        SL[i * 256 + t] = S[(size_t)b * 2048 + i * 256 + t];
    __syncthreads();

    // ---- PV + vcb -> XP (bf16, pre-swizzled B-operand layout) ----
    int col = t & 63, w = t >> 6;
    #pragma unroll
    for (int hh = 0; hh < 2; ++hh) {
        int h = w * 2 + hh;
        float v[16];
        #pragma unroll
        for (int d = 0; d < 16; ++d)
            v[d] = bf2f(V[((size_t)(b * 128 + h * 16 + d)) * HW + n0 + col]);
        float o[16];
        #pragma unroll
        for (int c = 0; c < 16; ++c) {
            const float* sl = SL + h * 256 + c * 16;
            float s = 0.f;
            #pragma unroll
            for (int d = 0; d < 16; ++d) s += sl[d] * v[d];
            o[c] = s + bf2f(vcb[((size_t)(b * 128 + h * 16 + c)) * HW + n0 + col]);
        }
        #pragma unroll
        for (int oc = 0; oc < 2; ++oc) {
            int octet = h * 2 + oc;
            int4 p;
            p.x = f2bf_pk(o[oc * 8 + 0], o[oc * 8 + 1]);
            p.y = f2bf_pk(o[oc * 8 + 2], o[oc * 8 + 3]);
            p.z = f2bf_pk(o[oc * 8 + 4], o[oc * 8 + 5]);
            p.w = f2bf_pk(o[oc * 8 + 6], o[oc * 8 + 7]);
            ((int4*)XP)[col * 16 + (octet ^ (col & 7))] = p;
        }
    }
    __syncthreads();

    int l = t & 63, kg = l >> 4, l15 = l & 15, l7 = l15 & 7;

    // ---- GEMM1': out_s = Wps @ (PV + vcb) (regs) ----
    f32x4 aP[2][4];
    #pragma unroll
    for (int mf = 0; mf < 2; ++mf)
        #pragma unroll
        for (int nf = 0; nf < 4; ++nf) aP[mf][nf] = (f32x4){0.f, 0.f, 0.f, 0.f};
    #pragma unroll
    for (int ks = 0; ks < 4; ++ks) {
        int ch = ks * 4 + kg;
        bf16x8 A0 = ((const bf16x8*)WL)[(w * 32 + l15) * 16 + (ch ^ l7)];
        bf16x8 A1 = ((const bf16x8*)WL)[(w * 32 + 16 + l15) * 16 + (ch ^ l7)];
        #pragma unroll
        for (int nf = 0; nf < 4; ++nf) {
            bf16x8 Bf = ((const bf16x8*)XP)[(nf * 16 + l15) * 16 + (ch ^ l7)];
            aP[0][nf] = __builtin_amdgcn_mfma_f32_16x16x32_bf16(A0, Bf, aP[0][nf], 0, 0, 0);
            aP[1][nf] = __builtin_amdgcn_mfma_f32_16x16x32_bf16(A1, Bf, aP[1][nf], 0, 0, 0);
        }
    }
    __syncthreads();   // WL (Wps) + XP (PV) reads done

    // ---- restage WL=Wpf; out_s^T -> XS; pre^T -> XP ----
    #pragma unroll
    for (int it = 0; it < 8; ++it)
        ((int4*)WL)[it * 256 + t] = wpf[it * 256 + t];
    #pragma unroll
    for (int mf = 0; mf < 2; ++mf)
        #pragma unroll
        for (int nf = 0; nf < 4; ++nf) {
            int cc = nf * 16 + l15;
            int r0 = w * 32 + mf * 16 + kg * 4;
            int octet = r0 >> 3;
            uint2 pk2;
            pk2.x = f2bf_pk(aP[mf][nf][0], aP[mf][nf][1]);
            pk2.y = f2bf_pk(aP[mf][nf][2], aP[mf][nf][3]);
            ((uint2*)XS)[(cc * 16 + (octet ^ (cc & 7))) * 2 + (kg & 1)] = pk2;
        }
    const unsigned short* pb = pre + (size_t)b * 128 * HW + n0;
    int nl = t & 63;
    #pragma unroll
    for (int it = 0; it < 4; ++it) {
        int c8 = (t >> 6) + it * 4;
        unsigned up[8];
        #pragma unroll
        for (int j = 0; j < 8; ++j)
            up[j] = pb[(size_t)(c8 * 8 + j) * HW + nl];
        int4 pp;
        pp.x = (int)(up[0] | (up[1] << 16)); pp.y = (int)(up[2] | (up[3] << 16));
        pp.z = (int)(up[4] | (up[5] << 16)); pp.w = (int)(up[6] | (up[7] << 16));
        ((int4*)XP)[nl * 16 + (c8 ^ (nl & 7))] = pp;
    }
    __syncthreads();

    // ---- GEMM1: out_f = Wpf @ pre ----
    f32x4 accF[2][4];
    #pragma unroll
    for (int mf = 0; mf < 2; ++mf)
        #pragma unroll
        for (int nf = 0; nf < 4; ++nf) accF[mf][nf] = (f32x4){0.f, 0.f, 0.f, 0.f};
    #pragma unroll
    for (int ks = 0; ks < 4; ++ks) {
        int ch = ks * 4 + kg;
        bf16x8 A0 = ((const bf16x8*)WL)[(w * 32 + l15) * 16 + (ch ^ l7)];
        bf16x8 A1 = ((const bf16x8*)WL)[(w * 32 + 16 + l15) * 16 + (ch ^ l7)];
        #pragma unroll
        for (int nf = 0; nf < 4; ++nf) {
            bf16x8 Bf = ((const bf16x8*)XP)[(nf * 16 + l15) * 16 + (ch ^ l7)];
            accF[0][nf] = __builtin_amdgcn_mfma_f32_16x16x32_bf16(A0, Bf, accF[0][nf], 0, 0, 0);
            accF[1][nf] = __builtin_amdgcn_mfma_f32_16x16x32_bf16(A1, Bf, accF[1][nf], 0, 0, 0);
        }
    }
    __syncthreads();   // WL (Wpf) + XP (pre) reads done

    // ---- restage WL=Wgsf; out_f^T -> XP ----
    #pragma unroll
    for (int it = 0; it < 8; ++it)
        ((int4*)WL)[it * 256 + t] = wgsf[it * 256 + t];
    #pragma unroll
    for (int mf = 0; mf < 2; ++mf)
        #pragma unroll
        for (int nf = 0; nf < 4; ++nf) {
            int cc = nf * 16 + l15;
            int r0 = w * 32 + mf * 16 + kg * 4;
            int octet = r0 >> 3;
            uint2 pk2;
            pk2.x = f2bf_pk(accF[mf][nf][0], accF[mf][nf][1]);
            pk2.y = f2bf_pk(accF[mf][nf][2], accF[mf][nf][3]);
            ((uint2*)XP)[(cc * 16 + (octet ^ (cc & 7))) * 2 + (kg & 1)] = pk2;
        }
    __syncthreads();

    // ---- GEMM2: aS = Wgsf @ out_s ----
    f32x4 aS[2][4];
    #pragma unroll
    for (int mf = 0; mf < 2; ++mf)
        #pragma unroll
        for (int nf = 0; nf < 4; ++nf) aS[mf][nf] = (f32x4){0.f, 0.f, 0.f, 0.f};
    #pragma unroll
    for (int ks = 0; ks < 4; ++ks) {
        int ch = ks * 4 + kg;
        bf16x8 A0 = ((const bf16x8*)WL)[(w * 32 + l15) * 16 + (ch ^ l7)];
        bf16x8 A1 = ((const bf16x8*)WL)[(w * 32 + 16 + l15) * 16 + (ch ^ l7)];
        #pragma unroll
        for (int nf = 0; nf < 4; ++nf) {
            bf16x8 Bf = ((const bf16x8*)XS)[(nf * 16 + l15) * 16 + (ch ^ l7)];
            aS[0][nf] = __builtin_amdgcn_mfma_f32_16x16x32_bf16(A0, Bf, aS[0][nf], 0, 0, 0);
            aS[1][nf] = __builtin_amdgcn_mfma_f32_16x16x32_bf16(A1, Bf, aS[1][nf], 0, 0, 0);
        }
    }
    __syncthreads();   // WL (Wgsf) reads done

    // ---- restage WL=Wgfs ----
    #pragma unroll
    for (int it = 0; it < 8; ++it)
        ((int4*)WL)[it * 256 + t] = wgfs[it * 256 + t];
    __syncthreads();

    // ---- GEMM3: aF = Wgfs @ out_f ----
    f32x4 aF[2][4];
    #pragma unroll
    for (int mf = 0; mf < 2; ++mf)
        #pragma unroll
        for (int nf = 0; nf < 4; ++nf) aF[mf][nf] = (f32x4){0.f, 0.f, 0.f, 0.f};
    #pragma unroll
    for (int ks = 0; ks < 4; ++ks) {
        int ch = ks * 4 + kg;
        bf16x8 A0 = ((const bf16x8*)WL)[(w * 32 + l15) * 16 + (ch ^ l7)];
        bf16x8 A1 = ((const bf16x8*)WL)[(w * 32 + 16 + l15) * 16 + (ch ^ l7)];
        #pragma unroll
        for (int nf = 0; nf < 4; ++nf) {
            bf16x8 Bf = ((const bf16x8*)XP)[(nf * 16 + l15) * 16 + (ch ^ l7)];
            aF[0][nf] = __builtin_amdgcn_mfma_f32_16x16x32_bf16(A0, Bf, aF[0][nf], 0, 0, 0);
            aF[1][nf] = __builtin_amdgcn_mfma_f32_16x16x32_bf16(A1, Bf, aF[1][nf], 0, 0, 0);
        }
    }

    // ---- epilogue: out = x + out_s*gs + out_f*gf (out_s from XS) ----
    #pragma unroll
    for (int mf = 0; mf < 2; ++mf)
        #pragma unroll
        for (int nf = 0; nf < 4; ++nf)
            #pragma unroll
            for (int i = 0; i < 4; ++i) {
                int row = w * 32 + mf * 16 + kg * 4 + i;
                int cc = nf * 16 + l15;
                float gf = sigmoidf_(aS[mf][nf][i] + bgsf[row]);   // gates out_f
                float gs = sigmoidf_(aF[mf][nf][i] + bgfs[row]);   // gates out_s
                size_t gi = ((size_t)(b * 128) + row) * HW + n0 + cc;
                float os = bf2f((unsigned short)XS[cc * 128 +
                                   (((row >> 3) ^ (cc & 7)) << 3) + (row & 7)]);
                float of = accF[mf][nf][i];
                out[gi] = x[gi] + os * gs + of * gf;
            }
}

// ---------------------------------------------------------------------------
// Fully-fused per-channel 2D FFT filter. Z = complex bf16 [128][128] in LDS.
// ZIX v2 (round-19 verified layout).
// ---------------------------------------------------------------------------
__device__ __forceinline__ int ZIX(int r, int j)
{
    return r * 128 + (j ^ (((r ^ (r >> 4)) & 3) << 3) ^ (((j >> 4) & 3) << 1));
}
__device__ __forceinline__ float2 zld(const unsigned* Z, int r, int j)
{
    unsigned z = Z[ZIX(r, j)];
    return make_float2(bf2f((unsigned short)(z & 0xFFFF)),
                       bf2f((unsigned short)(z >> 16)));
}
__device__ __forceinline__ void zst(unsigned* Z, int r, int j, float2 v)
{
    Z[ZIX(r, j)] = f2bf_pk(v.x, v.y);
}

__device__ __forceinline__ void dft16(float2* v)
{
    const float C1 = 0.92387953251f, S1 = 0.38268343236f, R2 = 0.70710678119f;
    const float2 W16[8] = {
        {1.f, 0.f}, {C1, -S1}, {R2, -R2}, {S1, -C1},
        {0.f, -1.f}, {-S1, -C1}, {-R2, -R2}, {-C1, -S1}};
    #pragma unroll
    for (int i = 0; i < 8; ++i) {
        float2 a = v[i], b = v[i + 8];
        v[i] = make_float2(a.x + b.x, a.y + b.y);
        float2 d = make_float2(a.x - b.x, a.y - b.y);
        v[i + 8] = cmul(d, W16[i]);
    }
    #pragma unroll
    for (int blk = 0; blk < 16; blk += 8)
        #pragma unroll
        for (int i = 0; i < 4; ++i) {
            float2 a = v[blk + i], b = v[blk + i + 4];
            v[blk + i] = make_float2(a.x + b.x, a.y + b.y);
            float2 d = make_float2(a.x - b.x, a.y - b.y);
            v[blk + i + 4] = cmul(d, W16[2 * i]);
        }
    #pragma unroll
    for (int blk = 0; blk < 16; blk += 4) {
        float2 a0 = v[blk], b0 = v[blk + 2];
        v[blk] = make_float2(a0.x + b0.x, a0.y + b0.y);
        v[blk + 2] = make_float2(a0.x - b0.x, a0.y - b0.y);
        float2 a1 = v[blk + 1], b1 = v[blk + 3];
        v[blk + 1] = make_float2(a1.x + b1.x, a1.y + b1.y);
        float2 d = make_float2(a1.x - b1.x, a1.y - b1.y);
        v[blk + 3] = make_float2(d.y, -d.x);          // * (0,-1)
    }
    #pragma unroll
    for (int blk = 0; blk < 16; blk += 2) {
        float2 a = v[blk], b = v[blk + 1];
        v[blk] = make_float2(a.x + b.x, a.y + b.y);
        v[blk + 1] = make_float2(a.x - b.x, a.y - b.y);
    }
}

__device__ __forceinline__ void dft8(float2* v)
{
    const float R2 = 0.70710678119f;
    const float2 W8[4] = {{1.f, 0.f}, {R2, -R2}, {0.f, -1.f}, {-R2, -R2}};
    #pragma unroll
    for (int i = 0; i < 4; ++i) {
        float2 a = v[i], b = v[i + 4];
        v[i] = make_float2(a.x + b.x, a.y + b.y);
        float2 d = make_float2(a.x - b.x, a.y - b.y);
        v[i + 4] = cmul(d, W8[i]);
    }
    #pragma unroll
    for (int blk = 0; blk < 8; blk += 4) {
        float2 a0 = v[blk], b0 = v[blk + 2];
        v[blk] = make_float2(a0.x + b0.x, a0.y + b0.y);
        v[blk + 2] = make_float2(a0.x - b0.x, a0.y - b0.y);
        float2 a1 = v[blk + 1], b1 = v[blk + 3];
        v[blk + 1] = make_float2(a1.x + b1.x, a1.y + b1.y);
        float2 d = make_float2(a1.x - b1.x, a1.y - b1.y);
        v[blk + 3] = make_float2(d.y, -d.x);
    }
    #pragma unroll
    for (int blk = 0; blk < 8; blk += 2) {
        float2 a = v[blk], b = v[blk + 1];
        v[blk] = make_float2(a.x + b.x, a.y + b.y);
        v[blk + 1] = make_float2(a.x - b.x, a.y - b.y);
    }
}

__device__ __forceinline__ void fft_line_row(unsigned* Z, const float2* tw,
                                             int row, int n2)
{
    const int BREV4[16] = {0,8,4,12,2,10,6,14,1,9,5,13,3,11,7,15};
    const int BREV3[8] = {0,4,2,6,1,5,3,7};
    float2 v[16];
    #pragma unroll
    for (int n1 = 0; n1 < 16; ++n1) v[n1] = zld(Z, row, 8 * n1 + n2);
    dft16(v);
    #pragma unroll
    for (int p = 0; p < 16; ++p) {
        int k1 = BREV4[p];
        zst(Z, row, 16 * n2 + k1, cmul(v[p], tw[n2 * k1]));
    }
    float2 wa[8], wb[8];
    #pragma unroll
    for (int m = 0; m < 8; ++m) {
        wa[m] = zld(Z, row, 16 * m + n2);
        wb[m] = zld(Z, row, 16 * m + n2 + 8);
    }
    dft8(wa);
    dft8(wb);
    #pragma unroll
    for (int p = 0; p < 8; ++p) {
        zst(Z, row, n2 + 16 * BREV3[p], wa[p]);
        zst(Z, row, n2 + 8 + 16 * BREV3[p], wb[p]);
    }
}

__device__ __forceinline__ void fft_line_col(unsigned* Z, const float2* tw,
                                             int col, int n2)
{
    const int BREV4[16] = {0,8,4,12,2,10,6,14,1,9,5,13,3,11,7,15};
    const int BREV3[8] = {0,4,2,6,1,5,3,7};
    float2 v[16];
    #pragma unroll
    for (int n1 = 0; n1 < 16; ++n1) v[n1] = zld(Z, 8 * n1 + n2, col);
    dft16(v);
    #pragma unroll
    for (int p = 0; p < 16; ++p) {
        int k1 = BREV4[p];
        zst(Z, 16 * n2 + k1, col, cmul(v[p], tw[n2 * k1]));
    }
    float2 wa[8], wb[8];
    #pragma unroll
    for (int m = 0; m < 8; ++m) {
        wa[m] = zld(Z, 16 * m + n2, col);
        wb[m] = zld(Z, 16 * m + n2 + 8, col);
    }
    dft8(wa);
    dft8(wb);
    #pragma unroll
    for (int p = 0; p < 8; ++p) {
        zst(Z, n2 + 16 * BREV3[p], col, wa[p]);
        zst(Z, n2 + 8 + 16 * BREV3[p], col, wb[p]);
    }
}

__global__ __launch_bounds__(256)
void fft_all_k(const unsigned short* __restrict__ xb,
               const unsigned short* __restrict__ sw,
               unsigned short* __restrict__ outp)
{
    __shared__ unsigned Z[128 * 128];   // 64 KB complex bf16
    __shared__ float2 tw[128];
    const int BREV3[8] = {0,4,2,6,1,5,3,7};
    int t = threadIdx.x;
    if (t < 128) {
        float sn, cs;
        sincosf(0.049087385212340519f * (float)t, &sn, &cs);
        tw[t] = make_float2(cs, -sn);
    }
    size_t base = (size_t)blockIdx.x * HW;

    // stage: Z = xb + i*sw (both bf16: pure bit-splice, vectorized)
    #pragma unroll
    for (int i = 0; i < 16; ++i) {
        int idx4 = (i * 256 + t) * 4;
        int r = idx4 >> 7, j = idx4 & 127;
        uint2 xv = *(const uint2*)(xb + base + idx4);
        uint2 sv = *(const uint2*)(sw + base + idx4);
        Z[ZIX(r, j + 0)] = (xv.x & 0xFFFFu) | (sv.x << 16);
        Z[ZIX(r, j + 1)] = (xv.x >> 16)     | (sv.x & 0xFFFF0000u);
        Z[ZIX(r, j + 2)] = (xv.y & 0xFFFFu) | (sv.y << 16);
        Z[ZIX(r, j + 3)] = (xv.y >> 16)     | (sv.y & 0xFFFF0000u);
    }
    __syncthreads();

    int ln = t >> 3, n2 = t & 7;
    #pragma unroll
    for (int it = 0; it < 4; ++it) fft_line_row(Z, tw, it * 32 + ln, n2);
    __syncthreads();
    #pragma unroll
    for (int it = 0; it < 4; ++it) fft_line_col(Z, tw, it * 32 + ln, n2);
    __syncthreads();

    // Hermitian split + product; store conj(Y) (inverse via fwd-on-conj)
    for (int item = t; item < 8194; item += 256) {
        int rA, kA, rB, kB;
        if (item < 8064) {
            rA = 1 + (item >> 7); kA = item & 127;
            rB = 128 - rA; kB = (128 - kA) & 127;
        } else {
            int it2 = item - 8064;
            rA = rB = (it2 < 65) ? 0 : 64;
            kA = (it2 < 65) ? it2 : (it2 - 65);
            kB = (128 - kA) & 127;
        }
        float2 z1 = zld(Z, rA, kA);
        float2 z2 = zld(Z, rB, kB);
        float2 X = make_float2(0.5f * (z1.x + z2.x), 0.5f * (z1.y - z2.y));
        float Dx = z1.x - z2.x, Dy = z1.y + z2.y;
        float2 Wf = make_float2(0.5f * Dy, -0.5f * Dx);
        float2 Y = cmul(X, Wf);
        zst(Z, rA, kA, make_float2(Y.x, -Y.y));
        zst(Z, rB, kB, Y);
    }
    __syncthreads();

    #pragma unroll
    for (int it = 0; it < 4; ++it) fft_line_col(Z, tw, it * 32 + ln, n2);
    __syncthreads();

    const float scale = 1.f / 2097152.f;   // 1/(128^3)
    const int BREV4[16] = {0,8,4,12,2,10,6,14,1,9,5,13,3,11,7,15};
    #pragma unroll
    for (int it = 0; it < 4; ++it) {
        int row = it * 32 + ln;
        float2 v[16];
        #pragma unroll
        for (int n1 = 0; n1 < 16; ++n1) v[n1] = zld(Z, row, 8 * n1 + n2);
        dft16(v);
        #pragma unroll
        for (int p = 0; p < 16; ++p) {
            int k1 = BREV4[p];
            zst(Z, row, 16 * n2 + k1, cmul(v[p], tw[n2 * k1]));
        }
        float2 wa[8], wb[8];
        #pragma unroll
        for (int m = 0; m < 8; ++m) {
            wa[m] = zld(Z, row, 16 * m + n2);
            wb[m] = zld(Z, row, 16 * m + n2 + 8);
        }
        dft8(wa);
        dft8(wb);
        #pragma unroll
        for (int p = 0; p < 8; ++p) {
            outp[base + row * 128 + n2 + 16 * BREV3[p]] = f2bf(wa[p].x * scale);
            outp[base + row * 128 + n2 + 8 + 16 * BREV3[p]] = f2bf(wb[p].x * scale);
        }
    }
}

// ---------------------------------------------------------------------------
// Workspace plan:
//  ws[0,32):   V bf16
//  ws[32,64):  vcb bf16 (moved from d_out: fused tail reads it while writing out)
//  ws[64,96):  swb bf16 -> pre bf16 (per-channel self-alias in fft_all_k)
//  ws[96,96.25): Wbf 7x32KB
//  ws[97,113): Gp (16 MB); G (512 KB) + S (64 KB) after
//  d_out[32,64): xb bf16 (dead after fft/gram; clobbered by tail's out write)
// ---------------------------------------------------------------------------
extern "C" void kernel_launch(void* const* d_in, const int* in_sizes, int n_in,
                              void* d_out, int out_size, void* d_ws, size_t ws_size,
                              hipStream_t stream)
{
    const float* x        = (const float*)d_in[0];
    const float* W_qkv    = (const float*)d_in[1];
    const float* W_dw     = (const float*)d_in[2];
    const float* W_proj_s = (const float*)d_in[3];
    const float* scale_s  = (const float*)d_in[4];
    const float* W_ff1    = (const float*)d_in[5];
    const float* W_ff2    = (const float*)d_in[6];
    const float* W_proj_f = (const float*)d_in[7];
    const float* W_gsf    = (const float*)d_in[8];
    const float* b_gsf    = (const float*)d_in[9];
    const float* W_gfs    = (const float*)d_in[10];
    const float* b_gfs    = (const float*)d_in[11];
    float* out = (float*)d_out;

    char* ws = (char*)d_ws;
    const size_t MB32 = 33554432ull;
    const size_t MB64 = 67108864ull;
    const size_t MB96 = 100663296ull;
    const size_t MB97 = 101711872ull;   // 97 MiB
    unsigned short* V     = (unsigned short*)(ws);          // 32 MiB
    unsigned short* vcb   = (unsigned short*)(ws + MB32);   // 32 MiB
    unsigned short* swb   = (unsigned short*)(ws + MB64);   // 32 MiB
    unsigned short* pre   = (unsigned short*)(ws + MB64);   // aliases swb (safe)
    int4* Wbf4            = (int4*)(ws + MB96);             // 224 KiB
    float* Gp  = (float*)(ws + MB97);                       // 16 MiB
    float* G   = Gp + 4194304;                              // 512 KiB
    float* S   = G + 131072;                                // 64 KiB
    unsigned short* xb  = (unsigned short*)out + 16777216;  // d_out[32,64)

    // slices: 0=W_v 1=W_proj_s 2=W_ff1 3=W_ff2 4=W_proj_f 5=W_gsf 6=W_gfs
    wprep_k<<<56, 256, 0, stream>>>(W_qkv + 256 * 128, W_proj_s, W_ff1, W_ff2,
                                    W_proj_f, W_gsf, W_gfs, Wbf4);

    // --- head: V = Wv@x, swb = ff2@gelu(ff1@x), xb = bf16(x) ---
    head_k<<<2048, 256, 0, stream>>>(x, Wbf4 + 0 * 2048, Wbf4 + 2 * 2048,
                                     Wbf4 + 3 * 2048, V, swb, xb);

    // --- spatial attention branch ---
    dwconv_k<<<1024, 256, 0, stream>>>(V, W_dw, vcb);
    gram_mfma_k<<<256, 256, 0, stream>>>(xb, Gp);
    gram_reduce_k<<<512, 256, 0, stream>>>(Gp, G);
    attn_s2_k<<<64, 256, 0, stream>>>(G, W_qkv, scale_s, S);

    // --- frequency branch: fused 2D-FFT filter ---
    fft_all_k<<<1024, 256, 0, stream>>>(xb, swb, pre);

    // --- fused tail: PV+proj_s + proj_f + gates + final output ---
    tail_k<<<2048, 256, 0, stream>>>(x, pre, V, vcb, S,
                                     Wbf4 + 1 * 2048, Wbf4 + 4 * 2048,
                                     Wbf4 + 5 * 2048, b_gsf,
                                     Wbf4 + 6 * 2048, b_gfs, out);
}

// Round 26
// 291.939 us; speedup vs baseline: 1.2873x; 1.2873x over previous
//
#include <hip/hip_runtime.h>
#include <hip/hip_bf16.h>
#include <math.h>

#define HW 16384

typedef __attribute__((ext_vector_type(8))) short bf16x8;
typedef __attribute__((ext_vector_type(4))) float f32x4;

__device__ __forceinline__ unsigned short f2bf(float a)
{
    __hip_bfloat16 h = __float2bfloat16(a);   // RNE, native v_cvt
    return __builtin_bit_cast(unsigned short, h);
}
__device__ __forceinline__ unsigned f2bf_pk(float a, float b)
{
    return (unsigned)f2bf(a) | ((unsigned)f2bf(b) << 16);
}
__device__ __forceinline__ float bf2f(unsigned short u)
{
    return __uint_as_float(((unsigned)u) << 16);
}
__device__ __forceinline__ float sigmoidf_(float v) { return 1.f / (1.f + expf(-v)); }

__device__ __forceinline__ float2 cmul(float2 a, float2 b)
{
    return make_float2(a.x * b.x - a.y * b.y, a.x * b.y + a.y * b.x);
}

// ---------------------------------------------------------------------------
// wprep: 7 weight matrices -> bf16 in pre-swizzled LDS chunk order.
// ---------------------------------------------------------------------------
__global__ __launch_bounds__(256)
void wprep_k(const float* __restrict__ w0, const float* __restrict__ w1,
             const float* __restrict__ w2, const float* __restrict__ w3,
             const float* __restrict__ w4, const float* __restrict__ w5,
             const float* __restrict__ w6, int4* __restrict__ Wbf4)
{
    int m = blockIdx.x >> 3;
    int slot = (blockIdx.x & 7) * 256 + threadIdx.x;   // 0..2047
    const float* src;
    switch (m) {
        case 0: src = w0; break;
        case 1: src = w1; break;
        case 2: src = w2; break;
        case 3: src = w3; break;
        case 4: src = w4; break;
        case 5: src = w5; break;
        default: src = w6; break;
    }
    int o = slot >> 4;
    int c16 = (slot & 15) ^ (o & 7);
    const float* p = src + o * 128 + c16 * 8;
    int4 pk;
    pk.x = f2bf_pk(p[0], p[1]); pk.y = f2bf_pk(p[2], p[3]);
    pk.z = f2bf_pk(p[4], p[5]); pk.w = f2bf_pk(p[6], p[7]);
    Wbf4[m * 2048 + slot] = pk;
}

// ---------------------------------------------------------------------------
// head: stage x once; V = Wv @ x ; swb = W_ff2 @ gelu(W_ff1 @ x);
// also emits xb = bf16(x) for gram/fft reuse.
// ---------------------------------------------------------------------------
__global__ __launch_bounds__(256)
void head_k(const float* __restrict__ x, const int4* __restrict__ wv,
            const int4* __restrict__ w1, const int4* __restrict__ w2,
            unsigned short* __restrict__ V, unsigned short* __restrict__ swb,
            unsigned short* __restrict__ xb)
{
    __shared__ short WL[128 * 128];   // 32 KB
    __shared__ short XLx[64 * 128];   // 16 KB
    __shared__ short XM[64 * 128];    // 16 KB
    int t = threadIdx.x;
    int gb = blockIdx.x;
    int b = gb >> 8;
    int n0 = (gb & 255) << 6;

    #pragma unroll
    for (int it = 0; it < 8; ++it)
        ((int4*)WL)[it * 256 + t] = wv[it * 256 + t];

    const float* inb = x + (size_t)b * 128 * HW + n0;
    int nl = t & 63;
    #pragma unroll
    for (int it = 0; it < 4; ++it) {
        int c8 = (t >> 6) + it * 4;
        float v[8];
        unsigned short vb[8];
        #pragma unroll
        for (int j = 0; j < 8; ++j) {
            v[j] = inb[(size_t)(c8 * 8 + j) * HW + nl];
            vb[j] = f2bf(v[j]);
            xb[((size_t)(b * 128) + c8 * 8 + j) * HW + n0 + nl] = vb[j];
        }
        int4 p;
        p.x = (int)((unsigned)vb[0] | ((unsigned)vb[1] << 16));
        p.y = (int)((unsigned)vb[2] | ((unsigned)vb[3] << 16));
        p.z = (int)((unsigned)vb[4] | ((unsigned)vb[5] << 16));
        p.w = (int)((unsigned)vb[6] | ((unsigned)vb[7] << 16));
        ((int4*)XLx)[nl * 16 + (c8 ^ (nl & 7))] = p;
    }
    __syncthreads();

    int l = t & 63, w = t >> 6, kg = l >> 4, l15 = l & 15, l7 = l15 & 7;

    // ---- GEMM1: V = Wv @ x ----
    f32x4 acc[2][4];
    #pragma unroll
    for (int mf = 0; mf < 2; ++mf)
        #pragma unroll
        for (int nf = 0; nf < 4; ++nf) acc[mf][nf] = (f32x4){0.f, 0.f, 0.f, 0.f};
    #pragma unroll
    for (int ks = 0; ks < 4; ++ks) {
        int ch = ks * 4 + kg;
        bf16x8 A0 = ((const bf16x8*)WL)[(w * 32 + l15) * 16 + (ch ^ l7)];
        bf16x8 A1 = ((const bf16x8*)WL)[(w * 32 + 16 + l15) * 16 + (ch ^ l7)];
        #pragma unroll
        for (int nf = 0; nf < 4; ++nf) {
            bf16x8 Bf = ((const bf16x8*)XLx)[(nf * 16 + l15) * 16 + (ch ^ l7)];
            acc[0][nf] = __builtin_amdgcn_mfma_f32_16x16x32_bf16(A0, Bf, acc[0][nf], 0, 0, 0);
            acc[1][nf] = __builtin_amdgcn_mfma_f32_16x16x32_bf16(A1, Bf, acc[1][nf], 0, 0, 0);
        }
    }
    #pragma unroll
    for (int mf = 0; mf < 2; ++mf)
        #pragma unroll
        for (int nf = 0; nf < 4; ++nf)
            #pragma unroll
            for (int i = 0; i < 4; ++i) {
                int row = w * 32 + mf * 16 + kg * 4 + i;
                int col = n0 + nf * 16 + l15;
                V[((size_t)b * 128 + row) * HW + col] = f2bf(acc[mf][nf][i]);
            }
    __syncthreads();

    #pragma unroll
    for (int it = 0; it < 8; ++it)
        ((int4*)WL)[it * 256 + t] = w1[it * 256 + t];
    __syncthreads();

    // ---- GEMM2: mid = ff1 @ x ----
    #pragma unroll
    for (int mf = 0; mf < 2; ++mf)
        #pragma unroll
        for (int nf = 0; nf < 4; ++nf) acc[mf][nf] = (f32x4){0.f, 0.f, 0.f, 0.f};
    #pragma unroll
    for (int ks = 0; ks < 4; ++ks) {
        int ch = ks * 4 + kg;
        bf16x8 A0 = ((const bf16x8*)WL)[(w * 32 + l15) * 16 + (ch ^ l7)];
        bf16x8 A1 = ((const bf16x8*)WL)[(w * 32 + 16 + l15) * 16 + (ch ^ l7)];
        #pragma unroll
        for (int nf = 0; nf < 4; ++nf) {
            bf16x8 Bf = ((const bf16x8*)XLx)[(nf * 16 + l15) * 16 + (ch ^ l7)];
            acc[0][nf] = __builtin_amdgcn_mfma_f32_16x16x32_bf16(A0, Bf, acc[0][nf], 0, 0, 0);
            acc[1][nf] = __builtin_amdgcn_mfma_f32_16x16x32_bf16(A1, Bf, acc[1][nf], 0, 0, 0);
        }
    }
    __syncthreads();

    #pragma unroll
    for (int it = 0; it < 8; ++it)
        ((int4*)WL)[it * 256 + t] = w2[it * 256 + t];
    #pragma unroll
    for (int mf = 0; mf < 2; ++mf)
        #pragma unroll
        for (int nf = 0; nf < 4; ++nf) {
            float g4[4];
            #pragma unroll
            for (int i = 0; i < 4; ++i) {
                float v = acc[mf][nf][i];
                g4[i] = 0.5f * v * (1.0f + erff(v * 0.70710678118654752f));
            }
            int col = nf * 16 + l15;
            int r0 = w * 32 + mf * 16 + kg * 4;
            int octet = r0 >> 3;
            uint2 pk2;
            pk2.x = f2bf_pk(g4[0], g4[1]);
            pk2.y = f2bf_pk(g4[2], g4[3]);
            ((uint2*)XM)[(col * 16 + (octet ^ (col & 7))) * 2 + (kg & 1)] = pk2;
        }
    __syncthreads();

    // ---- GEMM3: swb = ff2 @ mid ----
    f32x4 acc2[2][4];
    #pragma unroll
    for (int mf = 0; mf < 2; ++mf)
        #pragma unroll
        for (int nf = 0; nf < 4; ++nf) acc2[mf][nf] = (f32x4){0.f, 0.f, 0.f, 0.f};
    #pragma unroll
    for (int ks = 0; ks < 4; ++ks) {
        int ch = ks * 4 + kg;
        bf16x8 A0 = ((const bf16x8*)WL)[(w * 32 + l15) * 16 + (ch ^ l7)];
        bf16x8 A1 = ((const bf16x8*)WL)[(w * 32 + 16 + l15) * 16 + (ch ^ l7)];
        #pragma unroll
        for (int nf = 0; nf < 4; ++nf) {
            bf16x8 Bf = ((const bf16x8*)XM)[(nf * 16 + l15) * 16 + (ch ^ l7)];
            acc2[0][nf] = __builtin_amdgcn_mfma_f32_16x16x32_bf16(A0, Bf, acc2[0][nf], 0, 0, 0);
            acc2[1][nf] = __builtin_amdgcn_mfma_f32_16x16x32_bf16(A1, Bf, acc2[1][nf], 0, 0, 0);
        }
    }
    #pragma unroll
    for (int mf = 0; mf < 2; ++mf)
        #pragma unroll
        for (int nf = 0; nf < 4; ++nf)
            #pragma unroll
            for (int i = 0; i < 4; ++i) {
                int row = w * 32 + mf * 16 + kg * 4 + i;
                int col = n0 + nf * 16 + l15;
                swb[((size_t)b * 128 + row) * HW + col] = f2bf(acc2[mf][nf][i]);
            }
}

// ---------------------------------------------------------------------------
// depthwise 3x3 SAME, LDS-tiled: one block per (b,c) image plane (32 KB).
// ---------------------------------------------------------------------------
__global__ __launch_bounds__(256)
void dwconv_k(const unsigned short* __restrict__ V, const float* __restrict__ Wdw,
              unsigned short* __restrict__ vcb)
{
    __shared__ unsigned short Vt[128 * 128];   // 32 KB
    int t = threadIdx.x;
    int bc = blockIdx.x;
    int c = bc & 127;
    const unsigned short* vin = V + (size_t)bc * HW;
    #pragma unroll
    for (int i = 0; i < 16; ++i) {
        int idx = i * 256 + t;                 // uint2 chunks (4 px)
        ((uint2*)Vt)[idx] = ((const uint2*)vin)[idx];
    }
    float wf[9];
    #pragma unroll
    for (int i = 0; i < 9; ++i) wf[i] = Wdw[c * 9 + i];
    __syncthreads();
    #pragma unroll
    for (int i = 0; i < 16; ++i) {
        int q = i * 256 + t;
        int y = q >> 5;
        int x0 = (q & 31) << 2;
        float a0 = 0.f, a1 = 0.f, a2 = 0.f, a3 = 0.f;
        #pragma unroll
        for (int dy = 0; dy < 3; ++dy) {
            int yy = y + dy - 1;
            if (yy < 0 || yy > 127) continue;
            const unsigned short* r = Vt + yy * 128;
            uint2 mu = *(const uint2*)(r + x0);
            float m0 = bf2f((unsigned short)(mu.x & 0xFFFF));
            float m1 = bf2f((unsigned short)(mu.x >> 16));
            float m2 = bf2f((unsigned short)(mu.y & 0xFFFF));
            float m3 = bf2f((unsigned short)(mu.y >> 16));
            float left  = (x0 > 0)   ? bf2f(r[x0 - 1]) : 0.f;
            float right = (x0 < 124) ? bf2f(r[x0 + 4]) : 0.f;
            float w0 = wf[dy * 3], w1 = wf[dy * 3 + 1], w2 = wf[dy * 3 + 2];
            a0 += w0 * left + w1 * m0 + w2 * m1;
            a1 += w0 * m0   + w1 * m1 + w2 * m2;
            a2 += w0 * m1   + w1 * m2 + w2 * m3;
            a3 += w0 * m2   + w1 * m3 + w2 * right;
        }
        uint2 r2;
        r2.x = f2bf_pk(a0, a1);
        r2.y = f2bf_pk(a2, a3);
        *(uint2*)(vcb + (size_t)bc * HW + y * 128 + x0) = r2;
    }
}

// ---------------------------------------------------------------------------
// MFMA Gram partials (reads pre-converted xb: pure copy staging)
// ---------------------------------------------------------------------------
__global__ __launch_bounds__(256)
void gram_mfma_k(const unsigned short* __restrict__ xb, float* __restrict__ Gp)
{
    __shared__ short XL[128 * 128];
    int t = threadIdx.x;
    int blk = blockIdx.x;
    int b = blk >> 5, ks = blk & 31;
    const unsigned short* xbb = xb + (size_t)b * 128 * HW + ks * 512;
    int l = t & 63, w = t >> 6, kg = l >> 4, l15 = l & 15, l7 = l15 & 7;

    f32x4 acc[2][8];
    #pragma unroll
    for (int mf = 0; mf < 2; ++mf)
        #pragma unroll
        for (int nf = 0; nf < 8; ++nf) acc[mf][nf] = (f32x4){0.f, 0.f, 0.f, 0.f};

    for (int kc = 0; kc < 4; ++kc) {
        __syncthreads();
        #pragma unroll
        for (int it = 0; it < 8; ++it) {
            int g = it * 256 + t;
            int row = g >> 4, oct = g & 15;
            ((int4*)XL)[row * 16 + (oct ^ (row & 7))] =
                *(const int4*)(xbb + (size_t)row * HW + kc * 128 + oct * 8);
        }
        __syncthreads();
        #pragma unroll
        for (int s = 0; s < 4; ++s) {
            int oct = s * 4 + kg;
            bf16x8 A0 = ((const bf16x8*)XL)[(w * 32 + l15) * 16 + (oct ^ l7)];
            bf16x8 A1 = ((const bf16x8*)XL)[(w * 32 + 16 + l15) * 16 + (oct ^ l7)];
            #pragma unroll
            for (int nf = 0; nf < 8; ++nf) {
                bf16x8 Bf = ((const bf16x8*)XL)[(nf * 16 + l15) * 16 + (oct ^ l7)];
                acc[0][nf] = __builtin_amdgcn_mfma_f32_16x16x32_bf16(A0, Bf, acc[0][nf], 0, 0, 0);
                acc[1][nf] = __builtin_amdgcn_mfma_f32_16x16x32_bf16(A1, Bf, acc[1][nf], 0, 0, 0);
            }
        }
    }
    float* gp = Gp + (size_t)blk * 16384;
    #pragma unroll
    for (int mf = 0; mf < 2; ++mf)
        #pragma unroll
        for (int nf = 0; nf < 8; ++nf)
            #pragma unroll
            for (int i = 0; i < 4; ++i) {
                int row = w * 32 + mf * 16 + kg * 4 + i;
                int col = nf * 16 + l15;
                gp[row * 128 + col] = acc[mf][nf][i];
            }
}

__global__ void gram_reduce_k(const float* __restrict__ Gp, float* __restrict__ G)
{
    int idx = blockIdx.x * 256 + threadIdx.x;
    int b = idx >> 14;
    int ij = idx & 16383;
    const float* gp = Gp + (size_t)(b * 32) * 16384 + ij;
    float s = 0.f;
    #pragma unroll
    for (int ks = 0; ks < 32; ++ks) s += gp[(size_t)ks * 16384];
    G[idx] = s;
}

// ---------------------------------------------------------------------------
// S_h = softmax( (Wq_h G Wk_h^T) * scale[h] )
// ---------------------------------------------------------------------------
__global__ __launch_bounds__(256)
void attn_s2_k(const float* __restrict__ G, const float* __restrict__ Wqkv,
               const float* __restrict__ scale, float* __restrict__ S)
{
    __shared__ float Wq[16][129];
    __shared__ float Wk[16][129];
    __shared__ float Ts[16][129];
    int bh = blockIdx.x;
    int b = bh >> 3, h = bh & 7;
    int t = threadIdx.x;
    #pragma unroll
    for (int i = 0; i < 8; ++i) {
        int idx = t + i * 256;
        int r = idx >> 7, ci = idx & 127;
        Wq[r][ci] = Wqkv[(size_t)(h * 16 + r) * 128 + ci];
        Wk[r][ci] = Wqkv[(size_t)(128 + h * 16 + r) * 128 + ci];
    }
    __syncthreads();
    const float* Gb = G + (size_t)b * 16384;
    #pragma unroll
    for (int i = 0; i < 8; ++i) {
        int idx = t + i * 256;
        int c = idx >> 7, col = idx & 127;
        float s = 0.f;
        #pragma unroll 8
        for (int ci = 0; ci < 128; ++ci)
            s += Wq[c][ci] * Gb[ci * 128 + col];
        Ts[c][col] = s;
    }
    __syncthreads();
    int c = t >> 4, d = t & 15;
    float s = 0.f;
    #pragma unroll 8
    for (int col = 0; col < 128; ++col)
        s += Ts[c][col] * Wk[d][col];
    s *= scale[h];
    float m = s;
    #pragma unroll
    for (int w = 1; w < 16; w <<= 1)
        m = fmaxf(m, __shfl_xor(m, w, 64));
    float e = expf(s - m);
    float sum = e;
    #pragma unroll
    for (int w = 1; w < 16; w <<= 1)
        sum += __shfl_xor(sum, w, 64);
    S[(size_t)bh * 256 + t] = e / sum;
}

// ---------------------------------------------------------------------------
// proj_s with fused PV
// ---------------------------------------------------------------------------
__global__ __launch_bounds__(256)
void proj_s_pv_k(const unsigned short* __restrict__ V,
                 const unsigned short* __restrict__ vcb,
                 const float* __restrict__ S, const int4* __restrict__ wbf,
                 unsigned short* __restrict__ out_s)
{
    __shared__ short WL[128 * 128];
    __shared__ short XL[64 * 128];
    __shared__ float SL[2048];
    int t = threadIdx.x;
    int gb = blockIdx.x;
    int b = gb >> 8;
    int n0 = (gb & 255) << 6;

    #pragma unroll
    for (int it = 0; it < 8; ++it)
        ((int4*)WL)[it * 256 + t] = wbf[it * 256 + t];
    #pragma unroll
    for (int i = 0; i < 8; ++i)
        SL[i * 256 + t] = S[(size_t)b * 2048 + i * 256 + t];
    __syncthreads();

    int col = t & 63, w = t >> 6;
    #pragma unroll
    for (int hh = 0; hh < 2; ++hh) {
        int h = w * 2 + hh;
        float v[16];
        #pragma unroll
        for (int d = 0; d < 16; ++d)
            v[d] = bf2f(V[((size_t)(b * 128 + h * 16 + d)) * HW + n0 + col]);
        float o[16];
        #pragma unroll
        for (int c = 0; c < 16; ++c) {
            const float* sl = SL + h * 256 + c * 16;
            float s = 0.f;
            #pragma unroll
            for (int d = 0; d < 16; ++d) s += sl[d] * v[d];
            o[c] = s + bf2f(vcb[((size_t)(b * 128 + h * 16 + c)) * HW + n0 + col]);
        }
        #pragma unroll
        for (int oc = 0; oc < 2; ++oc) {
            int octet = h * 2 + oc;
            int4 p;
            p.x = f2bf_pk(o[oc * 8 + 0], o[oc * 8 + 1]);
            p.y = f2bf_pk(o[oc * 8 + 2], o[oc * 8 + 3]);
            p.z = f2bf_pk(o[oc * 8 + 4], o[oc * 8 + 5]);
            p.w = f2bf_pk(o[oc * 8 + 6], o[oc * 8 + 7]);
            ((int4*)XL)[col * 16 + (octet ^ (col & 7))] = p;
        }
    }
    __syncthreads();

    int l = t & 63, kg = l >> 4, l15 = l & 15, l7 = l15 & 7;
    f32x4 acc[2][4];
    #pragma unroll
    for (int mf = 0; mf < 2; ++mf)
        #pragma unroll
        for (int nf = 0; nf < 4; ++nf) acc[mf][nf] = (f32x4){0.f, 0.f, 0.f, 0.f};
    #pragma unroll
    for (int ks = 0; ks < 4; ++ks) {
        int ch = ks * 4 + kg;
        bf16x8 A0 = ((const bf16x8*)WL)[(w * 32 + l15) * 16 + (ch ^ l7)];
        bf16x8 A1 = ((const bf16x8*)WL)[(w * 32 + 16 + l15) * 16 + (ch ^ l7)];
        #pragma unroll
        for (int nf = 0; nf < 4; ++nf) {
            bf16x8 Bf = ((const bf16x8*)XL)[(nf * 16 + l15) * 16 + (ch ^ l7)];
            acc[0][nf] = __builtin_amdgcn_mfma_f32_16x16x32_bf16(A0, Bf, acc[0][nf], 0, 0, 0);
            acc[1][nf] = __builtin_amdgcn_mfma_f32_16x16x32_bf16(A1, Bf, acc[1][nf], 0, 0, 0);
        }
    }
    #pragma unroll
    for (int mf = 0; mf < 2; ++mf)
        #pragma unroll
        for (int nf = 0; nf < 4; ++nf)
            #pragma unroll
            for (int i = 0; i < 4; ++i) {
                int row = w * 32 + mf * 16 + kg * 4 + i;
                int colg = n0 + nf * 16 + l15;
                out_s[((size_t)b * 128 + row) * HW + colg] = f2bf(acc[mf][nf][i]);
            }
}

// ---------------------------------------------------------------------------
// tail: out_f = Wpf @ pre (regs + LDS^T); gates; final output.
// Epilogue reads out_s from XS (LDS) instead of global: -32 MB traffic.
// ---------------------------------------------------------------------------
__global__ __launch_bounds__(256)
void tail_k(const float* __restrict__ x, const unsigned short* __restrict__ outs,
            const unsigned short* __restrict__ pre,
            const int4* __restrict__ wpf,
            const int4* __restrict__ wgsf, const float* __restrict__ bgsf,
            const int4* __restrict__ wgfs, const float* __restrict__ bgfs,
            float* __restrict__ out)
{
    __shared__ short WL[128 * 128];   // 32 KB (Wpf -> Wgsf -> Wgfs)
    __shared__ short XP[64 * 128];    // 16 KB (pre^T, then out_f^T)
    __shared__ short XS[64 * 128];    // 16 KB (out_s^T, intact to the end)
    int t = threadIdx.x;
    int gb = blockIdx.x;
    int T = (gb & 7) * 256 + (gb >> 3);   // XCD swizzle (2048 % 8 == 0)
    int b = T >> 8;
    int n0 = (T & 255) << 6;

    #pragma unroll
    for (int it = 0; it < 8; ++it)
        ((int4*)WL)[it * 256 + t] = wpf[it * 256 + t];

    const unsigned short* pb = pre + (size_t)b * 128 * HW + n0;
    const unsigned short* sb = outs + (size_t)b * 128 * HW + n0;
    int nl = t & 63;
    #pragma unroll
    for (int it = 0; it < 4; ++it) {
        int c8 = (t >> 6) + it * 4;
        unsigned up[8], us[8];
        #pragma unroll
        for (int j = 0; j < 8; ++j) {
            size_t a = (size_t)(c8 * 8 + j) * HW + nl;
            up[j] = pb[a];
            us[j] = sb[a];
        }
        int4 pp, ps;
        pp.x = (int)(up[0] | (up[1] << 16)); pp.y = (int)(up[2] | (up[3] << 16));
        pp.z = (int)(up[4] | (up[5] << 16)); pp.w = (int)(up[6] | (up[7] << 16));
        ps.x = (int)(us[0] | (us[1] << 16)); ps.y = (int)(us[2] | (us[3] << 16));
        ps.z = (int)(us[4] | (us[5] << 16)); ps.w = (int)(us[6] | (us[7] << 16));
        ((int4*)XP)[nl * 16 + (c8 ^ (nl & 7))] = pp;
        ((int4*)XS)[nl * 16 + (c8 ^ (nl & 7))] = ps;
    }
    __syncthreads();

    int l = t & 63, w = t >> 6, kg = l >> 4, l15 = l & 15, l7 = l15 & 7;

    // ---- GEMM1: out_f = Wpf @ pre ----
    f32x4 accF[2][4];
    #pragma unroll
    for (int mf = 0; mf < 2; ++mf)
        #pragma unroll
        for (int nf = 0; nf < 4; ++nf) accF[mf][nf] = (f32x4){0.f, 0.f, 0.f, 0.f};
    #pragma unroll
    for (int ks = 0; ks < 4; ++ks) {
        int ch = ks * 4 + kg;
        bf16x8 A0 = ((const bf16x8*)WL)[(w * 32 + l15) * 16 + (ch ^ l7)];
        bf16x8 A1 = ((const bf16x8*)WL)[(w * 32 + 16 + l15) * 16 + (ch ^ l7)];
        #pragma unroll
        for (int nf = 0; nf < 4; ++nf) {
            bf16x8 Bf = ((const bf16x8*)XP)[(nf * 16 + l15) * 16 + (ch ^ l7)];
            accF[0][nf] = __builtin_amdgcn_mfma_f32_16x16x32_bf16(A0, Bf, accF[0][nf], 0, 0, 0);
            accF[1][nf] = __builtin_amdgcn_mfma_f32_16x16x32_bf16(A1, Bf, accF[1][nf], 0, 0, 0);
        }
    }
    __syncthreads();

    // ---- restage WL = Wgsf; write out_f^T into XP ----
    #pragma unroll
    for (int it = 0; it < 8; ++it)
        ((int4*)WL)[it * 256 + t] = wgsf[it * 256 + t];
    #pragma unroll
    for (int mf = 0; mf < 2; ++mf)
        #pragma unroll
        for (int nf = 0; nf < 4; ++nf) {
            int col = nf * 16 + l15;
            int r0 = w * 32 + mf * 16 + kg * 4;
            int octet = r0 >> 3;
            uint2 pk2;
            pk2.x = f2bf_pk(accF[mf][nf][0], accF[mf][nf][1]);
            pk2.y = f2bf_pk(accF[mf][nf][2], accF[mf][nf][3]);
            ((uint2*)XP)[(col * 16 + (octet ^ (col & 7))) * 2 + (kg & 1)] = pk2;
        }
    __syncthreads();

    // ---- GEMM2: aS = Wgsf @ out_s ----
    f32x4 aS[2][4];
    #pragma unroll
    for (int mf = 0; mf < 2; ++mf)
        #pragma unroll
        for (int nf = 0; nf < 4; ++nf) aS[mf][nf] = (f32x4){0.f, 0.f, 0.f, 0.f};
    #pragma unroll
    for (int ks = 0; ks < 4; ++ks) {
        int ch = ks * 4 + kg;
        bf16x8 A0 = ((const bf16x8*)WL)[(w * 32 + l15) * 16 + (ch ^ l7)];
        bf16x8 A1 = ((const bf16x8*)WL)[(w * 32 + 16 + l15) * 16 + (ch ^ l7)];
        #pragma unroll
        for (int nf = 0; nf < 4; ++nf) {
            bf16x8 Bf = ((const bf16x8*)XS)[(nf * 16 + l15) * 16 + (ch ^ l7)];
            aS[0][nf] = __builtin_amdgcn_mfma_f32_16x16x32_bf16(A0, Bf, aS[0][nf], 0, 0, 0);
            aS[1][nf] = __builtin_amdgcn_mfma_f32_16x16x32_bf16(A1, Bf, aS[1][nf], 0, 0, 0);
        }
    }
    __syncthreads();

    // ---- restage WL = Wgfs ----
    #pragma unroll
    for (int it = 0; it < 8; ++it)
        ((int4*)WL)[it * 256 + t] = wgfs[it * 256 + t];
    __syncthreads();

    // ---- GEMM3: aF = Wgfs @ out_f ----
    f32x4 aF[2][4];
    #pragma unroll
    for (int mf = 0; mf < 2; ++mf)
        #pragma unroll
        for (int nf = 0; nf < 4; ++nf) aF[mf][nf] = (f32x4){0.f, 0.f, 0.f, 0.f};
    #pragma unroll
    for (int ks = 0; ks < 4; ++ks) {
        int ch = ks * 4 + kg;
        bf16x8 A0 = ((const bf16x8*)WL)[(w * 32 + l15) * 16 + (ch ^ l7)];
        bf16x8 A1 = ((const bf16x8*)WL)[(w * 32 + 16 + l15) * 16 + (ch ^ l7)];
        #pragma unroll
        for (int nf = 0; nf < 4; ++nf) {
            bf16x8 Bf = ((const bf16x8*)XP)[(nf * 16 + l15) * 16 + (ch ^ l7)];
            aF[0][nf] = __builtin_amdgcn_mfma_f32_16x16x32_bf16(A0, Bf, aF[0][nf], 0, 0, 0);
            aF[1][nf] = __builtin_amdgcn_mfma_f32_16x16x32_bf16(A1, Bf, aF[1][nf], 0, 0, 0);
        }
    }

    // ---- epilogue: out = x + out_s*gs + out_f*gf  (out_s from XS in LDS) ----
    #pragma unroll
    for (int mf = 0; mf < 2; ++mf)
        #pragma unroll
        for (int nf = 0; nf < 4; ++nf)
            #pragma unroll
            for (int i = 0; i < 4; ++i) {
                int row = w * 32 + mf * 16 + kg * 4 + i;
                int cc = nf * 16 + l15;
                float gf = sigmoidf_(aS[mf][nf][i] + bgsf[row]);   // gates out_f
                float gs = sigmoidf_(aF[mf][nf][i] + bgfs[row]);   // gates out_s
                size_t gi = ((size_t)(b * 128) + row) * HW + n0 + cc;
                // out_s bits from LDS stage (identical to outs[gi]):
                float os = bf2f((unsigned short)XS[cc * 128 +
                                   (((row >> 3) ^ (cc & 7)) << 3) + (row & 7)]);
                float of = accF[mf][nf][i];
                out[gi] = x[gi] + os * gs + of * gf;
            }
}

// ---------------------------------------------------------------------------
// Fully-fused per-channel 2D FFT filter. Z = complex bf16 [128][128] in LDS.
// ZIX v2 layout; 512 threads (8 waves) for 16 waves/CU occupancy.
// ---------------------------------------------------------------------------
__device__ __forceinline__ int ZIX(int r, int j)
{
    return r * 128 + (j ^ (((r ^ (r >> 4)) & 3) << 3) ^ (((j >> 4) & 3) << 1));
}
__device__ __forceinline__ float2 zld(const unsigned* Z, int r, int j)
{
    unsigned z = Z[ZIX(r, j)];
    return make_float2(bf2f((unsigned short)(z & 0xFFFF)),
                       bf2f((unsigned short)(z >> 16)));
}
__device__ __forceinline__ void zst(unsigned* Z, int r, int j, float2 v)
{
    Z[ZIX(r, j)] = f2bf_pk(v.x, v.y);
}

__device__ __forceinline__ void dft16(float2* v)
{
    const float C1 = 0.92387953251f, S1 = 0.38268343236f, R2 = 0.70710678119f;
    const float2 W16[8] = {
        {1.f, 0.f}, {C1, -S1}, {R2, -R2}, {S1, -C1},
        {0.f, -1.f}, {-S1, -C1}, {-R2, -R2}, {-C1, -S1}};
    #pragma unroll
    for (int i = 0; i < 8; ++i) {
        float2 a = v[i], b = v[i + 8];
        v[i] = make_float2(a.x + b.x, a.y + b.y);
        float2 d = make_float2(a.x - b.x, a.y - b.y);
        v[i + 8] = cmul(d, W16[i]);
    }
    #pragma unroll
    for (int blk = 0; blk < 16; blk += 8)
        #pragma unroll
        for (int i = 0; i < 4; ++i) {
            float2 a = v[blk + i], b = v[blk + i + 4];
            v[blk + i] = make_float2(a.x + b.x, a.y + b.y);
            float2 d = make_float2(a.x - b.x, a.y - b.y);
            v[blk + i + 4] = cmul(d, W16[2 * i]);
        }
    #pragma unroll
    for (int blk = 0; blk < 16; blk += 4) {
        float2 a0 = v[blk], b0 = v[blk + 2];
        v[blk] = make_float2(a0.x + b0.x, a0.y + b0.y);
        v[blk + 2] = make_float2(a0.x - b0.x, a0.y - b0.y);
        float2 a1 = v[blk + 1], b1 = v[blk + 3];
        v[blk + 1] = make_float2(a1.x + b1.x, a1.y + b1.y);
        float2 d = make_float2(a1.x - b1.x, a1.y - b1.y);
        v[blk + 3] = make_float2(d.y, -d.x);          // * (0,-1)
    }
    #pragma unroll
    for (int blk = 0; blk < 16; blk += 2) {
        float2 a = v[blk], b = v[blk + 1];
        v[blk] = make_float2(a.x + b.x, a.y + b.y);
        v[blk + 1] = make_float2(a.x - b.x, a.y - b.y);
    }
}

__device__ __forceinline__ void dft8(float2* v)
{
    const float R2 = 0.70710678119f;
    const float2 W8[4] = {{1.f, 0.f}, {R2, -R2}, {0.f, -1.f}, {-R2, -R2}};
    #pragma unroll
    for (int i = 0; i < 4; ++i) {
        float2 a = v[i], b = v[i + 4];
        v[i] = make_float2(a.x + b.x, a.y + b.y);
        float2 d = make_float2(a.x - b.x, a.y - b.y);
        v[i + 4] = cmul(d, W8[i]);
    }
    #pragma unroll
    for (int blk = 0; blk < 8; blk += 4) {
        float2 a0 = v[blk], b0 = v[blk + 2];
        v[blk] = make_float2(a0.x + b0.x, a0.y + b0.y);
        v[blk + 2] = make_float2(a0.x - b0.x, a0.y - b0.y);
        float2 a1 = v[blk + 1], b1 = v[blk + 3];
        v[blk + 1] = make_float2(a1.x + b1.x, a1.y + b1.y);
        float2 d = make_float2(a1.x - b1.x, a1.y - b1.y);
        v[blk + 3] = make_float2(d.y, -d.x);
    }
    #pragma unroll
    for (int blk = 0; blk < 8; blk += 2) {
        float2 a = v[blk], b = v[blk + 1];
        v[blk] = make_float2(a.x + b.x, a.y + b.y);
        v[blk + 1] = make_float2(a.x - b.x, a.y - b.y);
    }
}

__device__ __forceinline__ void fft_line_row(unsigned* Z, const float2* tw,
                                             int row, int n2)
{
    const int BREV4[16] = {0,8,4,12,2,10,6,14,1,9,5,13,3,11,7,15};
    const int BREV3[8] = {0,4,2,6,1,5,3,7};
    float2 v[16];
    #pragma unroll
    for (int n1 = 0; n1 < 16; ++n1) v[n1] = zld(Z, row, 8 * n1 + n2);
    dft16(v);
    #pragma unroll
    for (int p = 0; p < 16; ++p) {
        int k1 = BREV4[p];
        zst(Z, row, 16 * n2 + k1, cmul(v[p], tw[n2 * k1]));
    }
    float2 wa[8], wb[8];
    #pragma unroll
    for (int m = 0; m < 8; ++m) {
        wa[m] = zld(Z, row, 16 * m + n2);
        wb[m] = zld(Z, row, 16 * m + n2 + 8);
    }
    dft8(wa);
    dft8(wb);
    #pragma unroll
    for (int p = 0; p < 8; ++p) {
        zst(Z, row, n2 + 16 * BREV3[p], wa[p]);
        zst(Z, row, n2 + 8 + 16 * BREV3[p], wb[p]);
    }
}

__device__ __forceinline__ void fft_line_col(unsigned* Z, const float2* tw,
                                             int col, int n2)
{
    const int BREV4[16] = {0,8,4,12,2,10,6,14,1,9,5,13,3,11,7,15};
    const int BREV3[8] = {0,4,2,6,1,5,3,7};
    float2 v[16];
    #pragma unroll
    for (int n1 = 0; n1 < 16; ++n1) v[n1] = zld(Z, 8 * n1 + n2, col);
    dft16(v);
    #pragma unroll
    for (int p = 0; p < 16; ++p) {
        int k1 = BREV4[p];
        zst(Z, 16 * n2 + k1, col, cmul(v[p], tw[n2 * k1]));
    }
    float2 wa[8], wb[8];
    #pragma unroll
    for (int m = 0; m < 8; ++m) {
        wa[m] = zld(Z, 16 * m + n2, col);
        wb[m] = zld(Z, 16 * m + n2 + 8, col);
    }
    dft8(wa);
    dft8(wb);
    #pragma unroll
    for (int p = 0; p < 8; ++p) {
        zst(Z, n2 + 16 * BREV3[p], col, wa[p]);
        zst(Z, n2 + 8 + 16 * BREV3[p], col, wb[p]);
    }
}

__global__ __launch_bounds__(512)
void fft_all_k(const unsigned short* __restrict__ xb,
               const unsigned short* __restrict__ sw,
               unsigned short* __restrict__ outp)
{
    __shared__ unsigned Z[128 * 128];   // 64 KB complex bf16
    __shared__ float2 tw[128];
    const int BREV3[8] = {0,4,2,6,1,5,3,7};
    int t = threadIdx.x;
    if (t < 128) {
        float sn, cs;
        sincosf(0.049087385212340519f * (float)t, &sn, &cs);
        tw[t] = make_float2(cs, -sn);
    }
    size_t base = (size_t)blockIdx.x * HW;

    // stage: Z = xb + i*sw (both bf16: pure bit-splice, vectorized)
    #pragma unroll
    for (int i = 0; i < 8; ++i) {
        int idx4 = (i * 512 + t) * 4;
        int r = idx4 >> 7, j = idx4 & 127;
        uint2 xv = *(const uint2*)(xb + base + idx4);
        uint2 sv = *(const uint2*)(sw + base + idx4);
        Z[ZIX(r, j + 0)] = (xv.x & 0xFFFFu) | (sv.x << 16);
        Z[ZIX(r, j + 1)] = (xv.x >> 16)     | (sv.x & 0xFFFF0000u);
        Z[ZIX(r, j + 2)] = (xv.y & 0xFFFFu) | (sv.y << 16);
        Z[ZIX(r, j + 3)] = (xv.y >> 16)     | (sv.y & 0xFFFF0000u);
    }
    __syncthreads();

    int ln = t >> 3, n2 = t & 7;    // ln in 0..63
    #pragma unroll
    for (int it = 0; it < 2; ++it) fft_line_row(Z, tw, it * 64 + ln, n2);
    __syncthreads();
    #pragma unroll
    for (int it = 0; it < 2; ++it) fft_line_col(Z, tw, it * 64 + ln, n2);
    __syncthreads();

    // Hermitian split + product; store conj(Y) (inverse via fwd-on-conj)
    for (int item = t; item < 8194; item += 512) {
        int rA, kA, rB, kB;
        if (item < 8064) {
            rA = 1 + (item >> 7); kA = item & 127;
            rB = 128 - rA; kB = (128 - kA) & 127;
        } else {
            int it2 = item - 8064;
            rA = rB = (it2 < 65) ? 0 : 64;
            kA = (it2 < 65) ? it2 : (it2 - 65);
            kB = (128 - kA) & 127;
        }
        float2 z1 = zld(Z, rA, kA);
        float2 z2 = zld(Z, rB, kB);
        float2 X = make_float2(0.5f * (z1.x + z2.x), 0.5f * (z1.y - z2.y));
        float Dx = z1.x - z2.x, Dy = z1.y + z2.y;
        float2 Wf = make_float2(0.5f * Dy, -0.5f * Dx);
        float2 Y = cmul(X, Wf);
        zst(Z, rA, kA, make_float2(Y.x, -Y.y));
        zst(Z, rB, kB, Y);
    }
    __syncthreads();

    #pragma unroll
    for (int it = 0; it < 2; ++it) fft_line_col(Z, tw, it * 64 + ln, n2);
    __syncthreads();

    const float scale = 1.f / 2097152.f;   // 1/(128^3)
    const int BREV4[16] = {0,8,4,12,2,10,6,14,1,9,5,13,3,11,7,15};
    #pragma unroll
    for (int it = 0; it < 2; ++it) {
        int row = it * 64 + ln;
        float2 v[16];
        #pragma unroll
        for (int n1 = 0; n1 < 16; ++n1) v[n1] = zld(Z, row, 8 * n1 + n2);
        dft16(v);
        #pragma unroll
        for (int p = 0; p < 16; ++p) {
            int k1 = BREV4[p];
            zst(Z, row, 16 * n2 + k1, cmul(v[p], tw[n2 * k1]));
        }
        float2 wa[8], wb[8];
        #pragma unroll
        for (int m = 0; m < 8; ++m) {
            wa[m] = zld(Z, row, 16 * m + n2);
            wb[m] = zld(Z, row, 16 * m + n2 + 8);
        }
        dft8(wa);
        dft8(wb);
        #pragma unroll
        for (int p = 0; p < 8; ++p) {
            outp[base + row * 128 + n2 + 16 * BREV3[p]] = f2bf(wa[p].x * scale);
            outp[base + row * 128 + n2 + 8 + 16 * BREV3[p]] = f2bf(wb[p].x * scale);
        }
    }
}

// ---------------------------------------------------------------------------
// Workspace plan:
//  ws[0,32):   V bf16
//  ws[32,64):  out_s bf16
//  ws[64,96):  swb bf16 -> pre bf16 (per-channel self-alias in fft_all_k)
//  ws[96,96.25): Wbf 7x32KB
//  ws[97,113): Gp (16 MB); G (512 KB) + S (64 KB) after
//  d_out[0,32):  vcb bf16   d_out[32,64): xb bf16   (both dead before tail)
// ---------------------------------------------------------------------------
extern "C" void kernel_launch(void* const* d_in, const int* in_sizes, int n_in,
                              void* d_out, int out_size, void* d_ws, size_t ws_size,
                              hipStream_t stream)
{
    const float* x        = (const float*)d_in[0];
    const float* W_qkv    = (const float*)d_in[1];
    const float* W_dw     = (const float*)d_in[2];
    const float* W_proj_s = (const float*)d_in[3];
    const float* scale_s  = (const float*)d_in[4];
    const float* W_ff1    = (const float*)d_in[5];
    const float* W_ff2    = (const float*)d_in[6];
    const float* W_proj_f = (const float*)d_in[7];
    const float* W_gsf    = (const float*)d_in[8];
    const float* b_gsf    = (const float*)d_in[9];
    const float* W_gfs    = (const float*)d_in[10];
    const float* b_gfs    = (const float*)d_in[11];
    float* out = (float*)d_out;

    char* ws = (char*)d_ws;
    const size_t MB32 = 33554432ull;
    const size_t MB64 = 67108864ull;
    const size_t MB96 = 100663296ull;
    const size_t MB97 = 101711872ull;   // 97 MiB
    unsigned short* V     = (unsigned short*)(ws);          // 32 MiB
    unsigned short* out_s = (unsigned short*)(ws + MB32);   // 32 MiB
    unsigned short* swb   = (unsigned short*)(ws + MB64);   // 32 MiB
    unsigned short* pre   = (unsigned short*)(ws + MB64);   // aliases swb (safe)
    int4* Wbf4            = (int4*)(ws + MB96);             // 224 KiB
    float* Gp  = (float*)(ws + MB97);                       // 16 MiB
    float* G   = Gp + 4194304;                              // 512 KiB
    float* S   = G + 131072;                                // 64 KiB
    unsigned short* vcb = (unsigned short*)out;             // d_out[0,32)
    unsigned short* xb  = (unsigned short*)out + 16777216;  // d_out[32,64)

    // slices: 0=W_v 1=W_proj_s 2=W_ff1 3=W_ff2 4=W_proj_f 5=W_gsf 6=W_gfs
    wprep_k<<<56, 256, 0, stream>>>(W_qkv + 256 * 128, W_proj_s, W_ff1, W_ff2,
                                    W_proj_f, W_gsf, W_gfs, Wbf4);

    // --- head: V = Wv@x, swb = ff2@gelu(ff1@x), xb = bf16(x) ---
    head_k<<<2048, 256, 0, stream>>>(x, Wbf4 + 0 * 2048, Wbf4 + 2 * 2048,
                                     Wbf4 + 3 * 2048, V, swb, xb);

    // --- spatial attention branch ---
    dwconv_k<<<1024, 256, 0, stream>>>(V, W_dw, vcb);
    gram_mfma_k<<<256, 256, 0, stream>>>(xb, Gp);
    gram_reduce_k<<<512, 256, 0, stream>>>(Gp, G);
    attn_s2_k<<<64, 256, 0, stream>>>(G, W_qkv, scale_s, S);
    proj_s_pv_k<<<2048, 256, 0, stream>>>(V, vcb, S, Wbf4 + 1 * 2048, out_s);

    // --- frequency branch: fused 2D-FFT filter (512 threads: 16 waves/CU) ---
    fft_all_k<<<1024, 512, 0, stream>>>(xb, swb, pre);

    // --- tail: proj_f + gates + final output ---
    tail_k<<<2048, 256, 0, stream>>>(x, out_s, pre, Wbf4 + 4 * 2048,
                                     Wbf4 + 5 * 2048, b_gsf,
                                     Wbf4 + 6 * 2048, b_gfs, out);
}

// Round 27
// 284.189 us; speedup vs baseline: 1.3224x; 1.0273x over previous
//
#include <hip/hip_runtime.h>
#include <hip/hip_bf16.h>
#include <math.h>

#define HW 16384

typedef __attribute__((ext_vector_type(8))) short bf16x8;
typedef __attribute__((ext_vector_type(4))) float f32x4;

__device__ __forceinline__ unsigned short f2bf(float a)
{
    __hip_bfloat16 h = __float2bfloat16(a);   // RNE, native v_cvt
    return __builtin_bit_cast(unsigned short, h);
}
__device__ __forceinline__ unsigned f2bf_pk(float a, float b)
{
    return (unsigned)f2bf(a) | ((unsigned)f2bf(b) << 16);
}
__device__ __forceinline__ float bf2f(unsigned short u)
{
    return __uint_as_float(((unsigned)u) << 16);
}
__device__ __forceinline__ float sigmoidf_(float v) { return 1.f / (1.f + expf(-v)); }

__device__ __forceinline__ float2 cmul(float2 a, float2 b)
{
    return make_float2(a.x * b.x - a.y * b.y, a.x * b.y + a.y * b.x);
}

// ---------------------------------------------------------------------------
// wprep: 7 weight matrices -> bf16 in pre-swizzled LDS chunk order.
// ---------------------------------------------------------------------------
__global__ __launch_bounds__(256)
void wprep_k(const float* __restrict__ w0, const float* __restrict__ w1,
             const float* __restrict__ w2, const float* __restrict__ w3,
             const float* __restrict__ w4, const float* __restrict__ w5,
             const float* __restrict__ w6, int4* __restrict__ Wbf4)
{
    int m = blockIdx.x >> 3;
    int slot = (blockIdx.x & 7) * 256 + threadIdx.x;   // 0..2047
    const float* src;
    switch (m) {
        case 0: src = w0; break;
        case 1: src = w1; break;
        case 2: src = w2; break;
        case 3: src = w3; break;
        case 4: src = w4; break;
        case 5: src = w5; break;
        default: src = w6; break;
    }
    int o = slot >> 4;
    int c16 = (slot & 15) ^ (o & 7);
    const float* p = src + o * 128 + c16 * 8;
    int4 pk;
    pk.x = f2bf_pk(p[0], p[1]); pk.y = f2bf_pk(p[2], p[3]);
    pk.z = f2bf_pk(p[4], p[5]); pk.w = f2bf_pk(p[6], p[7]);
    Wbf4[m * 2048 + slot] = pk;
}

// ---------------------------------------------------------------------------
// head: stage x once (float2 vectorized); V = Wv @ x ;
// swb = W_ff2 @ gelu(W_ff1 @ x); also emits xb = bf16(x) (uint stores).
// ---------------------------------------------------------------------------
__global__ __launch_bounds__(256)
void head_k(const float* __restrict__ x, const int4* __restrict__ wv,
            const int4* __restrict__ w1, const int4* __restrict__ w2,
            unsigned short* __restrict__ V, unsigned short* __restrict__ swb,
            unsigned short* __restrict__ xb)
{
    __shared__ short WL[128 * 128];   // 32 KB
    __shared__ short XLx[64 * 128];   // 16 KB
    __shared__ short XM[64 * 128];    // 16 KB
    int t = threadIdx.x;
    int gb = blockIdx.x;
    int b = gb >> 8;
    int n0 = (gb & 255) << 6;

    #pragma unroll
    for (int it = 0; it < 8; ++it)
        ((int4*)WL)[it * 256 + t] = wv[it * 256 + t];

    const float* inb = x + (size_t)b * 128 * HW + n0;
    int lp = t & 31;          // lane pair -> cols 2lp, 2lp+1
    int g = t >> 5;           // 0..7
    #pragma unroll
    for (int it = 0; it < 2; ++it) {
        int c8 = g + it * 8;  // 0..15
        unsigned lo[8], hi[8];
        #pragma unroll
        for (int j = 0; j < 8; ++j) {
            float2 v2 = *(const float2*)(inb + (size_t)(c8 * 8 + j) * HW + 2 * lp);
            unsigned pk = f2bf_pk(v2.x, v2.y);
            *(unsigned*)(xb + ((size_t)(b * 128) + c8 * 8 + j) * HW + n0 + 2 * lp) = pk;
            lo[j] = pk & 0xFFFFu;
            hi[j] = pk >> 16;
        }
        int4 p0, p1;
        p0.x = (int)(lo[0] | (lo[1] << 16)); p0.y = (int)(lo[2] | (lo[3] << 16));
        p0.z = (int)(lo[4] | (lo[5] << 16)); p0.w = (int)(lo[6] | (lo[7] << 16));
        p1.x = (int)(hi[0] | (hi[1] << 16)); p1.y = (int)(hi[2] | (hi[3] << 16));
        p1.z = (int)(hi[4] | (hi[5] << 16)); p1.w = (int)(hi[6] | (hi[7] << 16));
        int c0 = 2 * lp, c1 = 2 * lp + 1;
        ((int4*)XLx)[c0 * 16 + (c8 ^ (c0 & 7))] = p0;
        ((int4*)XLx)[c1 * 16 + (c8 ^ (c1 & 7))] = p1;
    }
    __syncthreads();

    int l = t & 63, w = t >> 6, kg = l >> 4, l15 = l & 15, l7 = l15 & 7;

    // ---- GEMM1: V = Wv @ x ----
    f32x4 acc[2][4];
    #pragma unroll
    for (int mf = 0; mf < 2; ++mf)
        #pragma unroll
        for (int nf = 0; nf < 4; ++nf) acc[mf][nf] = (f32x4){0.f, 0.f, 0.f, 0.f};
    #pragma unroll
    for (int ks = 0; ks < 4; ++ks) {
        int ch = ks * 4 + kg;
        bf16x8 A0 = ((const bf16x8*)WL)[(w * 32 + l15) * 16 + (ch ^ l7)];
        bf16x8 A1 = ((const bf16x8*)WL)[(w * 32 + 16 + l15) * 16 + (ch ^ l7)];
        #pragma unroll
        for (int nf = 0; nf < 4; ++nf) {
            bf16x8 Bf = ((const bf16x8*)XLx)[(nf * 16 + l15) * 16 + (ch ^ l7)];
            acc[0][nf] = __builtin_amdgcn_mfma_f32_16x16x32_bf16(A0, Bf, acc[0][nf], 0, 0, 0);
            acc[1][nf] = __builtin_amdgcn_mfma_f32_16x16x32_bf16(A1, Bf, acc[1][nf], 0, 0, 0);
        }
    }
    #pragma unroll
    for (int mf = 0; mf < 2; ++mf)
        #pragma unroll
        for (int nf = 0; nf < 4; ++nf)
            #pragma unroll
            for (int i = 0; i < 4; ++i) {
                int row = w * 32 + mf * 16 + kg * 4 + i;
                int col = n0 + nf * 16 + l15;
                V[((size_t)b * 128 + row) * HW + col] = f2bf(acc[mf][nf][i]);
            }
    __syncthreads();

    #pragma unroll
    for (int it = 0; it < 8; ++it)
        ((int4*)WL)[it * 256 + t] = w1[it * 256 + t];
    __syncthreads();

    // ---- GEMM2: mid = ff1 @ x ----
    #pragma unroll
    for (int mf = 0; mf < 2; ++mf)
        #pragma unroll
        for (int nf = 0; nf < 4; ++nf) acc[mf][nf] = (f32x4){0.f, 0.f, 0.f, 0.f};
    #pragma unroll
    for (int ks = 0; ks < 4; ++ks) {
        int ch = ks * 4 + kg;
        bf16x8 A0 = ((const bf16x8*)WL)[(w * 32 + l15) * 16 + (ch ^ l7)];
        bf16x8 A1 = ((const bf16x8*)WL)[(w * 32 + 16 + l15) * 16 + (ch ^ l7)];
        #pragma unroll
        for (int nf = 0; nf < 4; ++nf) {
            bf16x8 Bf = ((const bf16x8*)XLx)[(nf * 16 + l15) * 16 + (ch ^ l7)];
            acc[0][nf] = __builtin_amdgcn_mfma_f32_16x16x32_bf16(A0, Bf, acc[0][nf], 0, 0, 0);
            acc[1][nf] = __builtin_amdgcn_mfma_f32_16x16x32_bf16(A1, Bf, acc[1][nf], 0, 0, 0);
        }
    }
    __syncthreads();

    #pragma unroll
    for (int it = 0; it < 8; ++it)
        ((int4*)WL)[it * 256 + t] = w2[it * 256 + t];
    #pragma unroll
    for (int mf = 0; mf < 2; ++mf)
        #pragma unroll
        for (int nf = 0; nf < 4; ++nf) {
            float g4[4];
            #pragma unroll
            for (int i = 0; i < 4; ++i) {
                float v = acc[mf][nf][i];
                g4[i] = 0.5f * v * (1.0f + erff(v * 0.70710678118654752f));
            }
            int col = nf * 16 + l15;
            int r0 = w * 32 + mf * 16 + kg * 4;
            int octet = r0 >> 3;
            uint2 pk2;
            pk2.x = f2bf_pk(g4[0], g4[1]);
            pk2.y = f2bf_pk(g4[2], g4[3]);
            ((uint2*)XM)[(col * 16 + (octet ^ (col & 7))) * 2 + (kg & 1)] = pk2;
        }
    __syncthreads();

    // ---- GEMM3: swb = ff2 @ mid ----
    f32x4 acc2[2][4];
    #pragma unroll
    for (int mf = 0; mf < 2; ++mf)
        #pragma unroll
        for (int nf = 0; nf < 4; ++nf) acc2[mf][nf] = (f32x4){0.f, 0.f, 0.f, 0.f};
    #pragma unroll
    for (int ks = 0; ks < 4; ++ks) {
        int ch = ks * 4 + kg;
        bf16x8 A0 = ((const bf16x8*)WL)[(w * 32 + l15) * 16 + (ch ^ l7)];
        bf16x8 A1 = ((const bf16x8*)WL)[(w * 32 + 16 + l15) * 16 + (ch ^ l7)];
        #pragma unroll
        for (int nf = 0; nf < 4; ++nf) {
            bf16x8 Bf = ((const bf16x8*)XM)[(nf * 16 + l15) * 16 + (ch ^ l7)];
            acc2[0][nf] = __builtin_amdgcn_mfma_f32_16x16x32_bf16(A0, Bf, acc2[0][nf], 0, 0, 0);
            acc2[1][nf] = __builtin_amdgcn_mfma_f32_16x16x32_bf16(A1, Bf, acc2[1][nf], 0, 0, 0);
        }
    }
    #pragma unroll
    for (int mf = 0; mf < 2; ++mf)
        #pragma unroll
        for (int nf = 0; nf < 4; ++nf)
            #pragma unroll
            for (int i = 0; i < 4; ++i) {
                int row = w * 32 + mf * 16 + kg * 4 + i;
                int col = n0 + nf * 16 + l15;
                swb[((size_t)b * 128 + row) * HW + col] = f2bf(acc2[mf][nf][i]);
            }
}

// ---------------------------------------------------------------------------
// depthwise 3x3 SAME, LDS-tiled: one block per (b,c) image plane (32 KB).
// ---------------------------------------------------------------------------
__global__ __launch_bounds__(256)
void dwconv_k(const unsigned short* __restrict__ V, const float* __restrict__ Wdw,
              unsigned short* __restrict__ vcb)
{
    __shared__ unsigned short Vt[128 * 128];   // 32 KB
    int t = threadIdx.x;
    int bc = blockIdx.x;
    int c = bc & 127;
    const unsigned short* vin = V + (size_t)bc * HW;
    #pragma unroll
    for (int i = 0; i < 16; ++i) {
        int idx = i * 256 + t;                 // uint2 chunks (4 px)
        ((uint2*)Vt)[idx] = ((const uint2*)vin)[idx];
    }
    float wf[9];
    #pragma unroll
    for (int i = 0; i < 9; ++i) wf[i] = Wdw[c * 9 + i];
    __syncthreads();
    #pragma unroll
    for (int i = 0; i < 16; ++i) {
        int q = i * 256 + t;
        int y = q >> 5;
        int x0 = (q & 31) << 2;
        float a0 = 0.f, a1 = 0.f, a2 = 0.f, a3 = 0.f;
        #pragma unroll
        for (int dy = 0; dy < 3; ++dy) {
            int yy = y + dy - 1;
            if (yy < 0 || yy > 127) continue;
            const unsigned short* r = Vt + yy * 128;
            uint2 mu = *(const uint2*)(r + x0);
            float m0 = bf2f((unsigned short)(mu.x & 0xFFFF));
            float m1 = bf2f((unsigned short)(mu.x >> 16));
            float m2 = bf2f((unsigned short)(mu.y & 0xFFFF));
            float m3 = bf2f((unsigned short)(mu.y >> 16));
            float left  = (x0 > 0)   ? bf2f(r[x0 - 1]) : 0.f;
            float right = (x0 < 124) ? bf2f(r[x0 + 4]) : 0.f;
            float w0 = wf[dy * 3], w1 = wf[dy * 3 + 1], w2 = wf[dy * 3 + 2];
            a0 += w0 * left + w1 * m0 + w2 * m1;
            a1 += w0 * m0   + w1 * m1 + w2 * m2;
            a2 += w0 * m1   + w1 * m2 + w2 * m3;
            a3 += w0 * m2   + w1 * m3 + w2 * right;
        }
        uint2 r2;
        r2.x = f2bf_pk(a0, a1);
        r2.y = f2bf_pk(a2, a3);
        *(uint2*)(vcb + (size_t)bc * HW + y * 128 + x0) = r2;
    }
}

// ---------------------------------------------------------------------------
// MFMA Gram partials (reads pre-converted xb: pure copy staging)
// ---------------------------------------------------------------------------
__global__ __launch_bounds__(256)
void gram_mfma_k(const unsigned short* __restrict__ xb, float* __restrict__ Gp)
{
    __shared__ short XL[128 * 128];
    int t = threadIdx.x;
    int blk = blockIdx.x;
    int b = blk >> 5, ks = blk & 31;
    const unsigned short* xbb = xb + (size_t)b * 128 * HW + ks * 512;
    int l = t & 63, w = t >> 6, kg = l >> 4, l15 = l & 15, l7 = l15 & 7;

    f32x4 acc[2][8];
    #pragma unroll
    for (int mf = 0; mf < 2; ++mf)
        #pragma unroll
        for (int nf = 0; nf < 8; ++nf) acc[mf][nf] = (f32x4){0.f, 0.f, 0.f, 0.f};

    for (int kc = 0; kc < 4; ++kc) {
        __syncthreads();
        #pragma unroll
        for (int it = 0; it < 8; ++it) {
            int g = it * 256 + t;
            int row = g >> 4, oct = g & 15;
            ((int4*)XL)[row * 16 + (oct ^ (row & 7))] =
                *(const int4*)(xbb + (size_t)row * HW + kc * 128 + oct * 8);
        }
        __syncthreads();
        #pragma unroll
        for (int s = 0; s < 4; ++s) {
            int oct = s * 4 + kg;
            bf16x8 A0 = ((const bf16x8*)XL)[(w * 32 + l15) * 16 + (oct ^ l7)];
            bf16x8 A1 = ((const bf16x8*)XL)[(w * 32 + 16 + l15) * 16 + (oct ^ l7)];
            #pragma unroll
            for (int nf = 0; nf < 8; ++nf) {
                bf16x8 Bf = ((const bf16x8*)XL)[(nf * 16 + l15) * 16 + (oct ^ l7)];
                acc[0][nf] = __builtin_amdgcn_mfma_f32_16x16x32_bf16(A0, Bf, acc[0][nf], 0, 0, 0);
                acc[1][nf] = __builtin_amdgcn_mfma_f32_16x16x32_bf16(A1, Bf, acc[1][nf], 0, 0, 0);
            }
        }
    }
    float* gp = Gp + (size_t)blk * 16384;
    #pragma unroll
    for (int mf = 0; mf < 2; ++mf)
        #pragma unroll
        for (int nf = 0; nf < 8; ++nf)
            #pragma unroll
            for (int i = 0; i < 4; ++i) {
                int row = w * 32 + mf * 16 + kg * 4 + i;
                int col = nf * 16 + l15;
                gp[row * 128 + col] = acc[mf][nf][i];
            }
}

__global__ void gram_reduce_k(const float* __restrict__ Gp, float* __restrict__ G)
{
    int idx = blockIdx.x * 256 + threadIdx.x;
    int b = idx >> 14;
    int ij = idx & 16383;
    const float* gp = Gp + (size_t)(b * 32) * 16384 + ij;
    float s = 0.f;
    #pragma unroll
    for (int ks = 0; ks < 32; ++ks) s += gp[(size_t)ks * 16384];
    G[idx] = s;
}

// ---------------------------------------------------------------------------
// S_h = softmax( (Wq_h G Wk_h^T) * scale[h] )
// ---------------------------------------------------------------------------
__global__ __launch_bounds__(256)
void attn_s2_k(const float* __restrict__ G, const float* __restrict__ Wqkv,
               const float* __restrict__ scale, float* __restrict__ S)
{
    __shared__ float Wq[16][129];
    __shared__ float Wk[16][129];
    __shared__ float Ts[16][129];
    int bh = blockIdx.x;
    int b = bh >> 3, h = bh & 7;
    int t = threadIdx.x;
    #pragma unroll
    for (int i = 0; i < 8; ++i) {
        int idx = t + i * 256;
        int r = idx >> 7, ci = idx & 127;
        Wq[r][ci] = Wqkv[(size_t)(h * 16 + r) * 128 + ci];
        Wk[r][ci] = Wqkv[(size_t)(128 + h * 16 + r) * 128 + ci];
    }
    __syncthreads();
    const float* Gb = G + (size_t)b * 16384;
    #pragma unroll
    for (int i = 0; i < 8; ++i) {
        int idx = t + i * 256;
        int c = idx >> 7, col = idx & 127;
        float s = 0.f;
        #pragma unroll 8
        for (int ci = 0; ci < 128; ++ci)
            s += Wq[c][ci] * Gb[ci * 128 + col];
        Ts[c][col] = s;
    }
    __syncthreads();
    int c = t >> 4, d = t & 15;
    float s = 0.f;
    #pragma unroll 8
    for (int col = 0; col < 128; ++col)
        s += Ts[c][col] * Wk[d][col];
    s *= scale[h];
    float m = s;
    #pragma unroll
    for (int w = 1; w < 16; w <<= 1)
        m = fmaxf(m, __shfl_xor(m, w, 64));
    float e = expf(s - m);
    float sum = e;
    #pragma unroll
    for (int w = 1; w < 16; w <<= 1)
        sum += __shfl_xor(sum, w, 64);
    S[(size_t)bh * 256 + t] = e / sum;
}

// ---------------------------------------------------------------------------
// proj_s with fused PV
// ---------------------------------------------------------------------------
__global__ __launch_bounds__(256)
void proj_s_pv_k(const unsigned short* __restrict__ V,
                 const unsigned short* __restrict__ vcb,
                 const float* __restrict__ S, const int4* __restrict__ wbf,
                 unsigned short* __restrict__ out_s)
{
    __shared__ short WL[128 * 128];
    __shared__ short XL[64 * 128];
    __shared__ float SL[2048];
    int t = threadIdx.x;
    int gb = blockIdx.x;
    int b = gb >> 8;
    int n0 = (gb & 255) << 6;

    #pragma unroll
    for (int it = 0; it < 8; ++it)
        ((int4*)WL)[it * 256 + t] = wbf[it * 256 + t];
    #pragma unroll
    for (int i = 0; i < 8; ++i)
        SL[i * 256 + t] = S[(size_t)b * 2048 + i * 256 + t];
    __syncthreads();

    int col = t & 63, w = t >> 6;
    #pragma unroll
    for (int hh = 0; hh < 2; ++hh) {
        int h = w * 2 + hh;
        float v[16];
        #pragma unroll
        for (int d = 0; d < 16; ++d)
            v[d] = bf2f(V[((size_t)(b * 128 + h * 16 + d)) * HW + n0 + col]);
        float o[16];
        #pragma unroll
        for (int c = 0; c < 16; ++c) {
            const float* sl = SL + h * 256 + c * 16;
            float s = 0.f;
            #pragma unroll
            for (int d = 0; d < 16; ++d) s += sl[d] * v[d];
            o[c] = s + bf2f(vcb[((size_t)(b * 128 + h * 16 + c)) * HW + n0 + col]);
        }
        #pragma unroll
        for (int oc = 0; oc < 2; ++oc) {
            int octet = h * 2 + oc;
            int4 p;
            p.x = f2bf_pk(o[oc * 8 + 0], o[oc * 8 + 1]);
            p.y = f2bf_pk(o[oc * 8 + 2], o[oc * 8 + 3]);
            p.z = f2bf_pk(o[oc * 8 + 4], o[oc * 8 + 5]);
            p.w = f2bf_pk(o[oc * 8 + 6], o[oc * 8 + 7]);
            ((int4*)XL)[col * 16 + (octet ^ (col & 7))] = p;
        }
    }
    __syncthreads();

    int l = t & 63, kg = l >> 4, l15 = l & 15, l7 = l15 & 7;
    f32x4 acc[2][4];
    #pragma unroll
    for (int mf = 0; mf < 2; ++mf)
        #pragma unroll
        for (int nf = 0; nf < 4; ++nf) acc[mf][nf] = (f32x4){0.f, 0.f, 0.f, 0.f};
    #pragma unroll
    for (int ks = 0; ks < 4; ++ks) {
        int ch = ks * 4 + kg;
        bf16x8 A0 = ((const bf16x8*)WL)[(w * 32 + l15) * 16 + (ch ^ l7)];
        bf16x8 A1 = ((const bf16x8*)WL)[(w * 32 + 16 + l15) * 16 + (ch ^ l7)];
        #pragma unroll
        for (int nf = 0; nf < 4; ++nf) {
            bf16x8 Bf = ((const bf16x8*)XL)[(nf * 16 + l15) * 16 + (ch ^ l7)];
            acc[0][nf] = __builtin_amdgcn_mfma_f32_16x16x32_bf16(A0, Bf, acc[0][nf], 0, 0, 0);
            acc[1][nf] = __builtin_amdgcn_mfma_f32_16x16x32_bf16(A1, Bf, acc[1][nf], 0, 0, 0);
        }
    }
    #pragma unroll
    for (int mf = 0; mf < 2; ++mf)
        #pragma unroll
        for (int nf = 0; nf < 4; ++nf)
            #pragma unroll
            for (int i = 0; i < 4; ++i) {
                int row = w * 32 + mf * 16 + kg * 4 + i;
                int colg = n0 + nf * 16 + l15;
                out_s[((size_t)b * 128 + row) * HW + colg] = f2bf(acc[mf][nf][i]);
            }
}

// ---------------------------------------------------------------------------
// tail: out_f = Wpf @ pre (regs + LDS^T); gates; final output.
// Staging loads vectorized (uint = 2 bf16); epilogue reads out_s from XS.
// ---------------------------------------------------------------------------
__global__ __launch_bounds__(256)
void tail_k(const float* __restrict__ x, const unsigned short* __restrict__ outs,
            const unsigned short* __restrict__ pre,
            const int4* __restrict__ wpf,
            const int4* __restrict__ wgsf, const float* __restrict__ bgsf,
            const int4* __restrict__ wgfs, const float* __restrict__ bgfs,
            float* __restrict__ out)
{
    __shared__ short WL[128 * 128];   // 32 KB (Wpf -> Wgsf -> Wgfs)
    __shared__ short XP[64 * 128];    // 16 KB (pre^T, then out_f^T)
    __shared__ short XS[64 * 128];    // 16 KB (out_s^T, intact to the end)
    int t = threadIdx.x;
    int gb = blockIdx.x;
    int T = (gb & 7) * 256 + (gb >> 3);   // XCD swizzle (2048 % 8 == 0)
    int b = T >> 8;
    int n0 = (T & 255) << 6;

    #pragma unroll
    for (int it = 0; it < 8; ++it)
        ((int4*)WL)[it * 256 + t] = wpf[it * 256 + t];

    const unsigned short* pb = pre + (size_t)b * 128 * HW + n0;
    const unsigned short* sb = outs + (size_t)b * 128 * HW + n0;
    int lp = t & 31, g = t >> 5;
    #pragma unroll
    for (int it = 0; it < 2; ++it) {
        int c8 = g + it * 8;
        unsigned plo[8], phi[8], slo[8], shi[8];
        #pragma unroll
        for (int j = 0; j < 8; ++j) {
            size_t a = (size_t)(c8 * 8 + j) * HW + 2 * lp;
            unsigned pu = *(const unsigned*)(pb + a);
            unsigned su = *(const unsigned*)(sb + a);
            plo[j] = pu & 0xFFFFu; phi[j] = pu >> 16;
            slo[j] = su & 0xFFFFu; shi[j] = su >> 16;
        }
        int4 pp0, pp1, ps0, ps1;
        pp0.x = (int)(plo[0] | (plo[1] << 16)); pp0.y = (int)(plo[2] | (plo[3] << 16));
        pp0.z = (int)(plo[4] | (plo[5] << 16)); pp0.w = (int)(plo[6] | (plo[7] << 16));
        pp1.x = (int)(phi[0] | (phi[1] << 16)); pp1.y = (int)(phi[2] | (phi[3] << 16));
        pp1.z = (int)(phi[4] | (phi[5] << 16)); pp1.w = (int)(phi[6] | (phi[7] << 16));
        ps0.x = (int)(slo[0] | (slo[1] << 16)); ps0.y = (int)(slo[2] | (slo[3] << 16));
        ps0.z = (int)(slo[4] | (slo[5] << 16)); ps0.w = (int)(slo[6] | (slo[7] << 16));
        ps1.x = (int)(shi[0] | (shi[1] << 16)); ps1.y = (int)(shi[2] | (shi[3] << 16));
        ps1.z = (int)(shi[4] | (shi[5] << 16)); ps1.w = (int)(shi[6] | (shi[7] << 16));
        int c0 = 2 * lp, c1 = 2 * lp + 1;
        ((int4*)XP)[c0 * 16 + (c8 ^ (c0 & 7))] = pp0;
        ((int4*)XP)[c1 * 16 + (c8 ^ (c1 & 7))] = pp1;
        ((int4*)XS)[c0 * 16 + (c8 ^ (c0 & 7))] = ps0;
        ((int4*)XS)[c1 * 16 + (c8 ^ (c1 & 7))] = ps1;
    }
    __syncthreads();

    int l = t & 63, w = t >> 6, kg = l >> 4, l15 = l & 15, l7 = l15 & 7;

    // ---- GEMM1: out_f = Wpf @ pre ----
    f32x4 accF[2][4];
    #pragma unroll
    for (int mf = 0; mf < 2; ++mf)
        #pragma unroll
        for (int nf = 0; nf < 4; ++nf) accF[mf][nf] = (f32x4){0.f, 0.f, 0.f, 0.f};
    #pragma unroll
    for (int ks = 0; ks < 4; ++ks) {
        int ch = ks * 4 + kg;
        bf16x8 A0 = ((const bf16x8*)WL)[(w * 32 + l15) * 16 + (ch ^ l7)];
        bf16x8 A1 = ((const bf16x8*)WL)[(w * 32 + 16 + l15) * 16 + (ch ^ l7)];
        #pragma unroll
        for (int nf = 0; nf < 4; ++nf) {
            bf16x8 Bf = ((const bf16x8*)XP)[(nf * 16 + l15) * 16 + (ch ^ l7)];
            accF[0][nf] = __builtin_amdgcn_mfma_f32_16x16x32_bf16(A0, Bf, accF[0][nf], 0, 0, 0);
            accF[1][nf] = __builtin_amdgcn_mfma_f32_16x16x32_bf16(A1, Bf, accF[1][nf], 0, 0, 0);
        }
    }
    __syncthreads();

    // ---- restage WL = Wgsf; write out_f^T into XP ----
    #pragma unroll
    for (int it = 0; it < 8; ++it)
        ((int4*)WL)[it * 256 + t] = wgsf[it * 256 + t];
    #pragma unroll
    for (int mf = 0; mf < 2; ++mf)
        #pragma unroll
        for (int nf = 0; nf < 4; ++nf) {
            int col = nf * 16 + l15;
            int r0 = w * 32 + mf * 16 + kg * 4;
            int octet = r0 >> 3;
            uint2 pk2;
            pk2.x = f2bf_pk(accF[mf][nf][0], accF[mf][nf][1]);
            pk2.y = f2bf_pk(accF[mf][nf][2], accF[mf][nf][3]);
            ((uint2*)XP)[(col * 16 + (octet ^ (col & 7))) * 2 + (kg & 1)] = pk2;
        }
    __syncthreads();

    // ---- GEMM2: aS = Wgsf @ out_s ----
    f32x4 aS[2][4];
    #pragma unroll
    for (int mf = 0; mf < 2; ++mf)
        #pragma unroll
        for (int nf = 0; nf < 4; ++nf) aS[mf][nf] = (f32x4){0.f, 0.f, 0.f, 0.f};
    #pragma unroll
    for (int ks = 0; ks < 4; ++ks) {
        int ch = ks * 4 + kg;
        bf16x8 A0 = ((const bf16x8*)WL)[(w * 32 + l15) * 16 + (ch ^ l7)];
        bf16x8 A1 = ((const bf16x8*)WL)[(w * 32 + 16 + l15) * 16 + (ch ^ l7)];
        #pragma unroll
        for (int nf = 0; nf < 4; ++nf) {
            bf16x8 Bf = ((const bf16x8*)XS)[(nf * 16 + l15) * 16 + (ch ^ l7)];
            aS[0][nf] = __builtin_amdgcn_mfma_f32_16x16x32_bf16(A0, Bf, aS[0][nf], 0, 0, 0);
            aS[1][nf] = __builtin_amdgcn_mfma_f32_16x16x32_bf16(A1, Bf, aS[1][nf], 0, 0, 0);
        }
    }
    __syncthreads();

    // ---- restage WL = Wgfs ----
    #pragma unroll
    for (int it = 0; it < 8; ++it)
        ((int4*)WL)[it * 256 + t] = wgfs[it * 256 + t];
    __syncthreads();

    // ---- GEMM3: aF = Wgfs @ out_f ----
    f32x4 aF[2][4];
    #pragma unroll
    for (int mf = 0; mf < 2; ++mf)
        #pragma unroll
        for (int nf = 0; nf < 4; ++nf) aF[mf][nf] = (f32x4){0.f, 0.f, 0.f, 0.f};
    #pragma unroll
    for (int ks = 0; ks < 4; ++ks) {
        int ch = ks * 4 + kg;
        bf16x8 A0 = ((const bf16x8*)WL)[(w * 32 + l15) * 16 + (ch ^ l7)];
        bf16x8 A1 = ((const bf16x8*)WL)[(w * 32 + 16 + l15) * 16 + (ch ^ l7)];
        #pragma unroll
        for (int nf = 0; nf < 4; ++nf) {
            bf16x8 Bf = ((const bf16x8*)XP)[(nf * 16 + l15) * 16 + (ch ^ l7)];
            aF[0][nf] = __builtin_amdgcn_mfma_f32_16x16x32_bf16(A0, Bf, aF[0][nf], 0, 0, 0);
            aF[1][nf] = __builtin_amdgcn_mfma_f32_16x16x32_bf16(A1, Bf, aF[1][nf], 0, 0, 0);
        }
    }

    // ---- epilogue: out = x + out_s*gs + out_f*gf  (out_s from XS in LDS) ----
    #pragma unroll
    for (int mf = 0; mf < 2; ++mf)
        #pragma unroll
        for (int nf = 0; nf < 4; ++nf)
            #pragma unroll
            for (int i = 0; i < 4; ++i) {
                int row = w * 32 + mf * 16 + kg * 4 + i;
                int cc = nf * 16 + l15;
                float gf = sigmoidf_(aS[mf][nf][i] + bgsf[row]);   // gates out_f
                float gs = sigmoidf_(aF[mf][nf][i] + bgfs[row]);   // gates out_s
                size_t gi = ((size_t)(b * 128) + row) * HW + n0 + cc;
                // out_s bits from LDS stage (identical to outs[gi]):
                float os = bf2f((unsigned short)XS[cc * 128 +
                                   (((row >> 3) ^ (cc & 7)) << 3) + (row & 7)]);
                float of = accF[mf][nf][i];
                out[gi] = x[gi] + os * gs + of * gf;
            }
}

// ---------------------------------------------------------------------------
// Fully-fused per-channel 2D FFT filter. Z = complex bf16 [128][128] in LDS.
// ZIX v2 (round-19 verified layout). 256 threads (r24-verified config).
// ---------------------------------------------------------------------------
__device__ __forceinline__ int ZIX(int r, int j)
{
    return r * 128 + (j ^ (((r ^ (r >> 4)) & 3) << 3) ^ (((j >> 4) & 3) << 1));
}
__device__ __forceinline__ float2 zld(const unsigned* Z, int r, int j)
{
    unsigned z = Z[ZIX(r, j)];
    return make_float2(bf2f((unsigned short)(z & 0xFFFF)),
                       bf2f((unsigned short)(z >> 16)));
}
__device__ __forceinline__ void zst(unsigned* Z, int r, int j, float2 v)
{
    Z[ZIX(r, j)] = f2bf_pk(v.x, v.y);
}

__device__ __forceinline__ void dft16(float2* v)
{
    const float C1 = 0.92387953251f, S1 = 0.38268343236f, R2 = 0.70710678119f;
    const float2 W16[8] = {
        {1.f, 0.f}, {C1, -S1}, {R2, -R2}, {S1, -C1},
        {0.f, -1.f}, {-S1, -C1}, {-R2, -R2}, {-C1, -S1}};
    #pragma unroll
    for (int i = 0; i < 8; ++i) {
        float2 a = v[i], b = v[i + 8];
        v[i] = make_float2(a.x + b.x, a.y + b.y);
        float2 d = make_float2(a.x - b.x, a.y - b.y);
        v[i + 8] = cmul(d, W16[i]);
    }
    #pragma unroll
    for (int blk = 0; blk < 16; blk += 8)
        #pragma unroll
        for (int i = 0; i < 4; ++i) {
            float2 a = v[blk + i], b = v[blk + i + 4];
            v[blk + i] = make_float2(a.x + b.x, a.y + b.y);
            float2 d = make_float2(a.x - b.x, a.y - b.y);
            v[blk + i + 4] = cmul(d, W16[2 * i]);
        }
    #pragma unroll
    for (int blk = 0; blk < 16; blk += 4) {
        float2 a0 = v[blk], b0 = v[blk + 2];
        v[blk] = make_float2(a0.x + b0.x, a0.y + b0.y);
        v[blk + 2] = make_float2(a0.x - b0.x, a0.y - b0.y);
        float2 a1 = v[blk + 1], b1 = v[blk + 3];
        v[blk + 1] = make_float2(a1.x + b1.x, a1.y + b1.y);
        float2 d = make_float2(a1.x - b1.x, a1.y - b1.y);
        v[blk + 3] = make_float2(d.y, -d.x);          // * (0,-1)
    }
    #pragma unroll
    for (int blk = 0; blk < 16; blk += 2) {
        float2 a = v[blk], b = v[blk + 1];
        v[blk] = make_float2(a.x + b.x, a.y + b.y);
        v[blk + 1] = make_float2(a.x - b.x, a.y - b.y);
    }
}

__device__ __forceinline__ void dft8(float2* v)
{
    const float R2 = 0.70710678119f;
    const float2 W8[4] = {{1.f, 0.f}, {R2, -R2}, {0.f, -1.f}, {-R2, -R2}};
    #pragma unroll
    for (int i = 0; i < 4; ++i) {
        float2 a = v[i], b = v[i + 4];
        v[i] = make_float2(a.x + b.x, a.y + b.y);
        float2 d = make_float2(a.x - b.x, a.y - b.y);
        v[i + 4] = cmul(d, W8[i]);
    }
    #pragma unroll
    for (int blk = 0; blk < 8; blk += 4) {
        float2 a0 = v[blk], b0 = v[blk + 2];
        v[blk] = make_float2(a0.x + b0.x, a0.y + b0.y);
        v[blk + 2] = make_float2(a0.x - b0.x, a0.y - b0.y);
        float2 a1 = v[blk + 1], b1 = v[blk + 3];
        v[blk + 1] = make_float2(a1.x + b1.x, a1.y + b1.y);
        float2 d = make_float2(a1.x - b1.x, a1.y - b1.y);
        v[blk + 3] = make_float2(d.y, -d.x);
    }
    #pragma unroll
    for (int blk = 0; blk < 8; blk += 2) {
        float2 a = v[blk], b = v[blk + 1];
        v[blk] = make_float2(a.x + b.x, a.y + b.y);
        v[blk + 1] = make_float2(a.x - b.x, a.y - b.y);
    }
}

__device__ __forceinline__ void fft_line_row(unsigned* Z, const float2* tw,
                                             int row, int n2)
{
    const int BREV4[16] = {0,8,4,12,2,10,6,14,1,9,5,13,3,11,7,15};
    const int BREV3[8] = {0,4,2,6,1,5,3,7};
    float2 v[16];
    #pragma unroll
    for (int n1 = 0; n1 < 16; ++n1) v[n1] = zld(Z, row, 8 * n1 + n2);
    dft16(v);
    #pragma unroll
    for (int p = 0; p < 16; ++p) {
        int k1 = BREV4[p];
        zst(Z, row, 16 * n2 + k1, cmul(v[p], tw[n2 * k1]));
    }
    float2 wa[8], wb[8];
    #pragma unroll
    for (int m = 0; m < 8; ++m) {
        wa[m] = zld(Z, row, 16 * m + n2);
        wb[m] = zld(Z, row, 16 * m + n2 + 8);
    }
    dft8(wa);
    dft8(wb);
    #pragma unroll
    for (int p = 0; p < 8; ++p) {
        zst(Z, row, n2 + 16 * BREV3[p], wa[p]);
        zst(Z, row, n2 + 8 + 16 * BREV3[p], wb[p]);
    }
}

__device__ __forceinline__ void fft_line_col(unsigned* Z, const float2* tw,
                                             int col, int n2)
{
    const int BREV4[16] = {0,8,4,12,2,10,6,14,1,9,5,13,3,11,7,15};
    const int BREV3[8] = {0,4,2,6,1,5,3,7};
    float2 v[16];
    #pragma unroll
    for (int n1 = 0; n1 < 16; ++n1) v[n1] = zld(Z, 8 * n1 + n2, col);
    dft16(v);
    #pragma unroll
    for (int p = 0; p < 16; ++p) {
        int k1 = BREV4[p];
        zst(Z, 16 * n2 + k1, col, cmul(v[p], tw[n2 * k1]));
    }
    float2 wa[8], wb[8];
    #pragma unroll
    for (int m = 0; m < 8; ++m) {
        wa[m] = zld(Z, 16 * m + n2, col);
        wb[m] = zld(Z, 16 * m + n2 + 8, col);
    }
    dft8(wa);
    dft8(wb);
    #pragma unroll
    for (int p = 0; p < 8; ++p) {
        zst(Z, n2 + 16 * BREV3[p], col, wa[p]);
        zst(Z, n2 + 8 + 16 * BREV3[p], col, wb[p]);
    }
}

__global__ __launch_bounds__(256)
void fft_all_k(const unsigned short* __restrict__ xb,
               const unsigned short* __restrict__ sw,
               unsigned short* __restrict__ outp)
{
    __shared__ unsigned Z[128 * 128];   // 64 KB complex bf16
    __shared__ float2 tw[128];
    const int BREV3[8] = {0,4,2,6,1,5,3,7};
    int t = threadIdx.x;
    if (t < 128) {
        float sn, cs;
        sincosf(0.049087385212340519f * (float)t, &sn, &cs);
        tw[t] = make_float2(cs, -sn);
    }
    size_t base = (size_t)blockIdx.x * HW;

    // stage: Z = xb + i*sw (both bf16: pure bit-splice, vectorized)
    #pragma unroll
    for (int i = 0; i < 16; ++i) {
        int idx4 = (i * 256 + t) * 4;
        int r = idx4 >> 7, j = idx4 & 127;
        uint2 xv = *(const uint2*)(xb + base + idx4);
        uint2 sv = *(const uint2*)(sw + base + idx4);
        Z[ZIX(r, j + 0)] = (xv.x & 0xFFFFu) | (sv.x << 16);
        Z[ZIX(r, j + 1)] = (xv.x >> 16)     | (sv.x & 0xFFFF0000u);
        Z[ZIX(r, j + 2)] = (xv.y & 0xFFFFu) | (sv.y << 16);
        Z[ZIX(r, j + 3)] = (xv.y >> 16)     | (sv.y & 0xFFFF0000u);
    }
    __syncthreads();

    int ln = t >> 3, n2 = t & 7;
    #pragma unroll
    for (int it = 0; it < 4; ++it) fft_line_row(Z, tw, it * 32 + ln, n2);
    __syncthreads();
    #pragma unroll
    for (int it = 0; it < 4; ++it) fft_line_col(Z, tw, it * 32 + ln, n2);
    __syncthreads();

    // Hermitian split + product; store conj(Y) (inverse via fwd-on-conj)
    for (int item = t; item < 8194; item += 256) {
        int rA, kA, rB, kB;
        if (item < 8064) {
            rA = 1 + (item >> 7); kA = item & 127;
            rB = 128 - rA; kB = (128 - kA) & 127;
        } else {
            int it2 = item - 8064;
            rA = rB = (it2 < 65) ? 0 : 64;
            kA = (it2 < 65) ? it2 : (it2 - 65);
            kB = (128 - kA) & 127;
        }
        float2 z1 = zld(Z, rA, kA);
        float2 z2 = zld(Z, rB, kB);
        float2 X = make_float2(0.5f * (z1.x + z2.x), 0.5f * (z1.y - z2.y));
        float Dx = z1.x - z2.x, Dy = z1.y + z2.y;
        float2 Wf = make_float2(0.5f * Dy, -0.5f * Dx);
        float2 Y = cmul(X, Wf);
        zst(Z, rA, kA, make_float2(Y.x, -Y.y));
        zst(Z, rB, kB, Y);
    }
    __syncthreads();

    #pragma unroll
    for (int it = 0; it < 4; ++it) fft_line_col(Z, tw, it * 32 + ln, n2);
    __syncthreads();

    const float scale = 1.f / 2097152.f;   // 1/(128^3)
    const int BREV4[16] = {0,8,4,12,2,10,6,14,1,9,5,13,3,11,7,15};
    #pragma unroll
    for (int it = 0; it < 4; ++it) {
        int row = it * 32 + ln;
        float2 v[16];
        #pragma unroll
        for (int n1 = 0; n1 < 16; ++n1) v[n1] = zld(Z, row, 8 * n1 + n2);
        dft16(v);
        #pragma unroll
        for (int p = 0; p < 16; ++p) {
            int k1 = BREV4[p];
            zst(Z, row, 16 * n2 + k1, cmul(v[p], tw[n2 * k1]));
        }
        float2 wa[8], wb[8];
        #pragma unroll
        for (int m = 0; m < 8; ++m) {
            wa[m] = zld(Z, row, 16 * m + n2);
            wb[m] = zld(Z, row, 16 * m + n2 + 8);
        }
        dft8(wa);
        dft8(wb);
        #pragma unroll
        for (int p = 0; p < 8; ++p) {
            outp[base + row * 128 + n2 + 16 * BREV3[p]] = f2bf(wa[p].x * scale);
            outp[base + row * 128 + n2 + 8 + 16 * BREV3[p]] = f2bf(wb[p].x * scale);
        }
    }
}

// ---------------------------------------------------------------------------
// Workspace plan:
//  ws[0,32):   V bf16
//  ws[32,64):  out_s bf16
//  ws[64,96):  swb bf16 -> pre bf16 (per-channel self-alias in fft_all_k)
//  ws[96,96.25): Wbf 7x32KB
//  ws[97,113): Gp (16 MB); G (512 KB) + S (64 KB) after
//  d_out[0,32):  vcb bf16   d_out[32,64): xb bf16   (both dead before tail)
// ---------------------------------------------------------------------------
extern "C" void kernel_launch(void* const* d_in, const int* in_sizes, int n_in,
                              void* d_out, int out_size, void* d_ws, size_t ws_size,
                              hipStream_t stream)
{
    const float* x        = (const float*)d_in[0];
    const float* W_qkv    = (const float*)d_in[1];
    const float* W_dw     = (const float*)d_in[2];
    const float* W_proj_s = (const float*)d_in[3];
    const float* scale_s  = (const float*)d_in[4];
    const float* W_ff1    = (const float*)d_in[5];
    const float* W_ff2    = (const float*)d_in[6];
    const float* W_proj_f = (const float*)d_in[7];
    const float* W_gsf    = (const float*)d_in[8];
    const float* b_gsf    = (const float*)d_in[9];
    const float* W_gfs    = (const float*)d_in[10];
    const float* b_gfs    = (const float*)d_in[11];
    float* out = (float*)d_out;

    char* ws = (char*)d_ws;
    const size_t MB32 = 33554432ull;
    const size_t MB64 = 67108864ull;
    const size_t MB96 = 100663296ull;
    const size_t MB97 = 101711872ull;   // 97 MiB
    unsigned short* V     = (unsigned short*)(ws);          // 32 MiB
    unsigned short* out_s = (unsigned short*)(ws + MB32);   // 32 MiB
    unsigned short* swb   = (unsigned short*)(ws + MB64);   // 32 MiB
    unsigned short* pre   = (unsigned short*)(ws + MB64);   // aliases swb (safe)
    int4* Wbf4            = (int4*)(ws + MB96);             // 224 KiB
    float* Gp  = (float*)(ws + MB97);                       // 16 MiB
    float* G   = Gp + 4194304;                              // 512 KiB
    float* S   = G + 131072;                                // 64 KiB
    unsigned short* vcb = (unsigned short*)out;             // d_out[0,32)
    unsigned short* xb  = (unsigned short*)out + 16777216;  // d_out[32,64)

    // slices: 0=W_v 1=W_proj_s 2=W_ff1 3=W_ff2 4=W_proj_f 5=W_gsf 6=W_gfs
    wprep_k<<<56, 256, 0, stream>>>(W_qkv + 256 * 128, W_proj_s, W_ff1, W_ff2,
                                    W_proj_f, W_gsf, W_gfs, Wbf4);

    // --- head: V = Wv@x, swb = ff2@gelu(ff1@x), xb = bf16(x) ---
    head_k<<<2048, 256, 0, stream>>>(x, Wbf4 + 0 * 2048, Wbf4 + 2 * 2048,
                                     Wbf4 + 3 * 2048, V, swb, xb);

    // --- spatial attention branch ---
    dwconv_k<<<1024, 256, 0, stream>>>(V, W_dw, vcb);
    gram_mfma_k<<<256, 256, 0, stream>>>(xb, Gp);
    gram_reduce_k<<<512, 256, 0, stream>>>(Gp, G);
    attn_s2_k<<<64, 256, 0, stream>>>(G, W_qkv, scale_s, S);
    proj_s_pv_k<<<2048, 256, 0, stream>>>(V, vcb, S, Wbf4 + 1 * 2048, out_s);

    // --- frequency branch: fused 2D-FFT filter ---
    fft_all_k<<<1024, 256, 0, stream>>>(xb, swb, pre);

    // --- tail: proj_f + gates + final output ---
    tail_k<<<2048, 256, 0, stream>>>(x, out_s, pre, Wbf4 + 4 * 2048,
                                     Wbf4 + 5 * 2048, b_gsf,
                                     Wbf4 + 6 * 2048, b_gfs, out);
}